// Round 1
// baseline (1894.246 us; speedup 1.0000x reference)
//
#include <hip/hip_runtime.h>
#include <stdint.h>

#define DEV __device__ __forceinline__

typedef __bf16 bf16x8 __attribute__((ext_vector_type(8)));
typedef float  f32x4  __attribute__((ext_vector_type(4)));

struct alignas(8) U16x4 { uint16_t x, y, z, w; };

DEV uint16_t f2bf(float f) {
  union { float f; uint32_t u; } v; v.f = f;
  uint32_t r = v.u + 0x7fffu + ((v.u >> 16) & 1u);
  return (uint16_t)(r >> 16);
}

DEV void gload16(const void* g, void* l) {
  __builtin_amdgcn_global_load_lds((__attribute__((address_space(1))) void*)(g),
                                   (__attribute__((address_space(3))) void*)(l),
                                   16, 0, 0);
}

// ---------------------------------------------------------------------------
// Weight transpose + f32->bf16:  in [R][C] f32  ->  out [C][R] bf16
// ---------------------------------------------------------------------------
__global__ __launch_bounds__(1024) void transpose_cvt(
    const float* __restrict__ in, uint16_t* __restrict__ out, int R, int C) {
  __shared__ float tile[32][33];
  const int tx = threadIdx.x, ty = threadIdx.y;
  const int r = blockIdx.y * 32 + ty, c = blockIdx.x * 32 + tx;
  tile[ty][tx] = in[(size_t)r * C + c];
  __syncthreads();
  const int oc = blockIdx.x * 32 + ty;   // output row (former column)
  const int orr = blockIdx.y * 32 + tx;  // output col (former row)
  out[(size_t)oc * R + orr] = f2bf(tile[tx][ty]);
}

// ---------------------------------------------------------------------------
// Slice src into modal1/modal2 token-major bf16 [16384][1024]
// ---------------------------------------------------------------------------
__global__ __launch_bounds__(256) void cvt_modal(
    const float* __restrict__ src, uint16_t* __restrict__ m1, uint16_t* __restrict__ m2) {
  const int idx = blockIdx.x * 256 + threadIdx.x;  // float4 group
  const int E = idx * 4;
  const int t = E >> 10, dd = E & 1023;
  const size_t s1 = ((size_t)(t >> 7) * 256 + (t & 127)) * 1024 + dd;
  float4 a = *(const float4*)&src[s1];
  float4 b = *(const float4*)&src[s1 + 131072];  // s + 128 rows
  U16x4 pa{f2bf(a.x), f2bf(a.y), f2bf(a.z), f2bf(a.w)};
  U16x4 pb{f2bf(b.x), f2bf(b.y), f2bf(b.z), f2bf(b.w)};
  *(U16x4*)&m1[E] = pa;
  *(U16x4*)&m2[E] = pb;
}

// ---------------------------------------------------------------------------
// GEMM: C[M][N] = A[M][K] @ Bt[N][K]^T + bias (+relu) (+resid)
// m97 structure: 128x128 tile, BK=32, 4 waves (2x2), global_load_lds staging.
// RESID: 0 none, 1 plain f32 [M][1024], 2 strided src slice (soff)
// ---------------------------------------------------------------------------
template <int RESID, bool RELU, bool OUTF32>
__global__ __launch_bounds__(256, 2) void gemm_bt(
    const uint16_t* __restrict__ A, const uint16_t* __restrict__ Bt,
    const float* __restrict__ bias, const float* __restrict__ resid,
    void* __restrict__ outp, int M, int N, int K, int nbn, int soff) {
  __shared__ uint16_t sA[128 * 32];
  __shared__ uint16_t sB[128 * 32];
  const int bid = blockIdx.x;
  const int bn = bid % nbn, bm = bid / nbn;
  const int brow = bm << 7, bcol = bn << 7;
  const int tid = threadIdx.x;
  const int w = tid >> 6, lane = tid & 63, l15 = lane & 15, lhi = lane >> 4;
  const int wr = w >> 1, wc = w & 1;

  f32x4 acc[4][4];
  const f32x4 z = {0.f, 0.f, 0.f, 0.f};
  for (int m = 0; m < 4; ++m)
    for (int n = 0; n < 4; ++n) acc[m][n] = z;

  // staging coords: wave w stages rows [(w*2+i)*16, +16) of each 128x32 tile
  const int srow0 = (w * 2) * 16 + (lane >> 2);
  const int srow1 = (w * 2 + 1) * 16 + (lane >> 2);
  const int schunk = (lane & 3) * 8;
  const uint16_t* Ag0 = A + (size_t)(brow + srow0) * K + schunk;
  const uint16_t* Ag1 = A + (size_t)(brow + srow1) * K + schunk;
  const uint16_t* Bg0 = Bt + (size_t)(bcol + srow0) * K + schunk;
  const uint16_t* Bg1 = Bt + (size_t)(bcol + srow1) * K + schunk;
  uint16_t* la0 = &sA[(w * 2) * 512];      // wave-uniform LDS bases
  uint16_t* la1 = &sA[(w * 2 + 1) * 512];
  uint16_t* lb0 = &sB[(w * 2) * 512];
  uint16_t* lb1 = &sB[(w * 2 + 1) * 512];

  for (int k0 = 0; k0 < K; k0 += 32) {
    __syncthreads();  // previous iteration's reads done
    gload16(Ag0 + k0, la0);
    gload16(Ag1 + k0, la1);
    gload16(Bg0 + k0, lb0);
    gload16(Bg1 + k0, lb1);
    __syncthreads();  // staging drained (vmcnt(0) before barrier)
    bf16x8 av[4], bv[4];
#pragma unroll
    for (int m = 0; m < 4; ++m)
      av[m] = *(const bf16x8*)&sA[(wr * 64 + m * 16 + l15) * 32 + lhi * 8];
#pragma unroll
    for (int n = 0; n < 4; ++n)
      bv[n] = *(const bf16x8*)&sB[(wc * 64 + n * 16 + l15) * 32 + lhi * 8];
#pragma unroll
    for (int m = 0; m < 4; ++m)
#pragma unroll
      for (int n = 0; n < 4; ++n)
        acc[m][n] = __builtin_amdgcn_mfma_f32_16x16x32_bf16(av[m], bv[n], acc[m][n], 0, 0, 0);
  }

#pragma unroll
  for (int n = 0; n < 4; ++n) {
    const int col = bcol + wc * 64 + n * 16 + l15;
    const float bs = bias[col];
#pragma unroll
    for (int m = 0; m < 4; ++m) {
#pragma unroll
      for (int r = 0; r < 4; ++r) {
        const int row = brow + wr * 64 + m * 16 + lhi * 4 + r;
        float v = acc[m][n][r] + bs;
        if (RELU) v = fmaxf(v, 0.f);
        if (RESID == 1) v += resid[(size_t)row * 1024 + col];
        if (RESID == 2)
          v += resid[((size_t)(row >> 7) * 256 + soff + (row & 127)) * 1024 + col];
        if (OUTF32)
          ((float*)outp)[(size_t)row * N + col] = v;
        else
          ((uint16_t*)outp)[(size_t)row * N + col] = f2bf(v);
      }
    }
  }
}

// ---------------------------------------------------------------------------
// Attention core: one block per (b,h). S=128, dh=64. Q,K,V bf16 [t][1024].
// ---------------------------------------------------------------------------
__global__ __launch_bounds__(256) void attn_kern(
    const uint16_t* __restrict__ Q, const uint16_t* __restrict__ Kv,
    const uint16_t* __restrict__ V, uint16_t* __restrict__ O) {
  __shared__ uint16_t sm[24576];  // 48 KB: [Q 16K | K 16K | Vt 16K]; P aliases Q+K
  uint16_t* sQ = sm;
  uint16_t* sK = sm + 8192;
  uint16_t* sVt = sm + 16384;
  uint16_t* sP = sm;  // 128x128 bf16 = 32KB, reuses Q+K after barrier
  const int bh = blockIdx.x, b = bh >> 4, h = bh & 15;
  const int tid = threadIdx.x, w = tid >> 6, lane = tid & 63, l15 = lane & 15, lhi = lane >> 4;
  const size_t base = (size_t)b * 131072 + h * 64;

  // stage Q, K row-major [128][64]
  for (int i = 0; i < 4; ++i) {
    const int gidx = i * 256 + tid;
    const int row = gidx >> 3, co = (gidx & 7) * 8;
    *(uint4*)&sQ[row * 64 + co] = *(const uint4*)&Q[base + (size_t)row * 1024 + co];
    *(uint4*)&sK[row * 64 + co] = *(const uint4*)&Kv[base + (size_t)row * 1024 + co];
  }
  // stage V transposed: sVt[c][key]
  {
    const int r = tid >> 1, cb = (tid & 1) * 32;
    for (int jj = 0; jj < 4; ++jj) {
      uint4 vv = *(const uint4*)&V[base + (size_t)r * 1024 + cb + jj * 8];
      const uint16_t* e = (const uint16_t*)&vv;
      for (int j = 0; j < 8; ++j) sVt[(cb + jj * 8 + j) * 128 + r] = e[j];
    }
  }
  __syncthreads();

  // QK^T: wave w owns q-rows [w*32, +32)
  f32x4 s[2][8];
  const f32x4 z = {0.f, 0.f, 0.f, 0.f};
  for (int m = 0; m < 2; ++m)
    for (int n = 0; n < 8; ++n) s[m][n] = z;
#pragma unroll
  for (int kk = 0; kk < 2; ++kk) {
    bf16x8 aq[2];
#pragma unroll
    for (int m = 0; m < 2; ++m)
      aq[m] = *(const bf16x8*)&sQ[(w * 32 + m * 16 + l15) * 64 + kk * 32 + lhi * 8];
#pragma unroll
    for (int n = 0; n < 8; ++n) {
      bf16x8 bk = *(const bf16x8*)&sK[(n * 16 + l15) * 64 + kk * 32 + lhi * 8];
#pragma unroll
      for (int m = 0; m < 2; ++m)
        s[m][n] = __builtin_amdgcn_mfma_f32_16x16x32_bf16(aq[m], bk, s[m][n], 0, 0, 0);
    }
  }

  // softmax over keys (row lives across 16 lanes sharing lhi, cols = n, l15)
  for (int m = 0; m < 2; ++m) {
    float mx[4], sum[4];
#pragma unroll
    for (int r = 0; r < 4; ++r) {
      float v = s[m][0][r];
      for (int n = 1; n < 8; ++n) v = fmaxf(v, s[m][n][r]);
      for (int msk = 1; msk < 16; msk <<= 1) v = fmaxf(v, __shfl_xor(v, msk, 64));
      mx[r] = v;
      sum[r] = 0.f;
    }
    for (int n = 0; n < 8; ++n)
      for (int r = 0; r < 4; ++r) {
        float e = __expf((s[m][n][r] - mx[r]) * 0.125f);  // 1/sqrt(64)
        s[m][n][r] = e;
        sum[r] += e;
      }
#pragma unroll
    for (int r = 0; r < 4; ++r) {
      float t = sum[r];
      for (int msk = 1; msk < 16; msk <<= 1) t += __shfl_xor(t, msk, 64);
      sum[r] = 1.f / t;
    }
    for (int n = 0; n < 8; ++n)
      for (int r = 0; r < 4; ++r) s[m][n][r] *= sum[r];
  }
  __syncthreads();  // all waves done reading sQ/sK before P overwrite

  for (int m = 0; m < 2; ++m)
    for (int n = 0; n < 8; ++n)
      for (int r = 0; r < 4; ++r)
        sP[(w * 32 + m * 16 + lhi * 4 + r) * 128 + n * 16 + l15] = f2bf(s[m][n][r]);
  __syncthreads();

  // PV: out[32][64] per wave
  f32x4 o[2][4];
  for (int m = 0; m < 2; ++m)
    for (int n = 0; n < 4; ++n) o[m][n] = z;
#pragma unroll
  for (int kk = 0; kk < 4; ++kk) {
    bf16x8 ap[2];
#pragma unroll
    for (int m = 0; m < 2; ++m)
      ap[m] = *(const bf16x8*)&sP[(w * 32 + m * 16 + l15) * 128 + kk * 32 + lhi * 8];
#pragma unroll
    for (int n = 0; n < 4; ++n) {
      bf16x8 bv = *(const bf16x8*)&sVt[(n * 16 + l15) * 128 + kk * 32 + lhi * 8];
#pragma unroll
      for (int m = 0; m < 2; ++m)
        o[m][n] = __builtin_amdgcn_mfma_f32_16x16x32_bf16(ap[m], bv, o[m][n], 0, 0, 0);
    }
  }
  for (int m = 0; m < 2; ++m)
    for (int n = 0; n < 4; ++n)
      for (int r = 0; r < 4; ++r) {
        const int q = w * 32 + m * 16 + lhi * 4 + r, c = n * 16 + l15;
        O[base + (size_t)q * 1024 + c] = f2bf(o[m][n][r]);
      }
}

// ---------------------------------------------------------------------------
// LN2D: per-batch-element layernorm over 128x1024, affine g/beta [128][1024].
// outf strided by bstride; optional bf16 copy (contiguous [b][131072]).
// ---------------------------------------------------------------------------
__global__ __launch_bounds__(256) void ln2d(
    const float* __restrict__ x, const float* __restrict__ g, const float* __restrict__ bet,
    float* __restrict__ outf, int bstride, uint16_t* __restrict__ outbf) {
  const int b = blockIdx.x, tid = threadIdx.x;
  const float4* xb = (const float4*)(x + (size_t)b * 131072);
  float s = 0.f, ss = 0.f;
  for (int i = tid; i < 32768; i += 256) {
    float4 v = xb[i];
    s += (v.x + v.y) + (v.z + v.w);
    ss += (v.x * v.x + v.y * v.y) + (v.z * v.z + v.w * v.w);
  }
#pragma unroll
  for (int m = 1; m < 64; m <<= 1) {
    s += __shfl_xor(s, m, 64);
    ss += __shfl_xor(ss, m, 64);
  }
  __shared__ float red[8];
  __shared__ float stats[2];
  const int w = tid >> 6;
  if ((tid & 63) == 0) {
    red[w] = s;
    red[4 + w] = ss;
  }
  __syncthreads();
  if (tid == 0) {
    const float S = red[0] + red[1] + red[2] + red[3];
    const float SS = red[4] + red[5] + red[6] + red[7];
    const float mu = S * (1.f / 131072.f);
    const float var = SS * (1.f / 131072.f) - mu * mu;
    stats[0] = mu;
    stats[1] = rsqrtf(var + 1e-5f);
  }
  __syncthreads();
  const float mu = stats[0], rs = stats[1];
  float* of = outf + (size_t)b * (size_t)bstride;
  uint16_t* ob = outbf ? outbf + (size_t)b * 131072 : nullptr;
  const float4* g4 = (const float4*)g;
  const float4* b4 = (const float4*)bet;
  for (int i = tid; i < 32768; i += 256) {
    float4 v = xb[i], gg = g4[i], bb = b4[i];
    float4 o;
    o.x = (v.x - mu) * rs * gg.x + bb.x;
    o.y = (v.y - mu) * rs * gg.y + bb.y;
    o.z = (v.z - mu) * rs * gg.z + bb.z;
    o.w = (v.w - mu) * rs * gg.w + bb.w;
    *(float4*)&of[(size_t)i * 4] = o;
    if (ob) {
      U16x4 u{f2bf(o.x), f2bf(o.y), f2bf(o.z), f2bf(o.w)};
      *(U16x4*)&ob[(size_t)i * 4] = u;
    }
  }
}

// ---------------------------------------------------------------------------
extern "C" void kernel_launch(void* const* d_in, const int* in_sizes, int n_in,
                              void* d_out, int out_size, void* d_ws, size_t ws_size,
                              hipStream_t stream) {
  const float* src = (const float*)d_in[0];
  const float* Wq = (const float*)d_in[1];
  const float* bq = (const float*)d_in[2];
  const float* Wk = (const float*)d_in[3];
  const float* bk = (const float*)d_in[4];
  const float* Wv = (const float*)d_in[5];
  const float* bv = (const float*)d_in[6];
  const float* Wo = (const float*)d_in[7];
  const float* bo = (const float*)d_in[8];
  const float* W1 = (const float*)d_in[9];
  const float* b1 = (const float*)d_in[10];
  const float* W2 = (const float*)d_in[11];
  const float* b2 = (const float*)d_in[12];
  const float* g1 = (const float*)d_in[13];
  const float* be1 = (const float*)d_in[14];
  const float* g2 = (const float*)d_in[15];
  const float* be2 = (const float*)d_in[16];
  float* dout = (float*)d_out;
  char* ws = (char*)d_ws;

  const size_t MB = 1024 * 1024;
  uint16_t* wq_t = (uint16_t*)(ws + 0 * MB);
  uint16_t* wk_t = (uint16_t*)(ws + 2 * MB);
  uint16_t* wv_t = (uint16_t*)(ws + 4 * MB);
  uint16_t* wo_t = (uint16_t*)(ws + 6 * MB);
  uint16_t* w1_t = (uint16_t*)(ws + 8 * MB);   // [4096][1024]
  uint16_t* w2_t = (uint16_t*)(ws + 16 * MB);  // [1024][4096]
  uint16_t* m1bf = (uint16_t*)(ws + 24 * MB);  // final m1 bf16 (phase-B KV src)
  uint16_t* mod2 = (uint16_t*)(ws + 56 * MB);
  uint16_t* QB = (uint16_t*)(ws + 88 * MB);
  uint16_t* KB = (uint16_t*)(ws + 120 * MB);
  uint16_t* VB = (uint16_t*)(ws + 152 * MB);
  uint16_t* ATT = (uint16_t*)(ws + 184 * MB);
  uint16_t* Hbf = QB;  // 128 MB FFN hidden aliases QB..ATT (dead by then)
  uint16_t* mod1 = (uint16_t*)(ws + 216 * MB);
  float* XA = (float*)(ws + 248 * MB);
  float* YF = (float*)(ws + 312 * MB);
  uint16_t* YBF = (uint16_t*)(ws + 376 * MB);
  // total: 408 MB

  dim3 tb(32, 32);
  transpose_cvt<<<dim3(32, 32), tb, 0, stream>>>(Wq, wq_t, 1024, 1024);
  transpose_cvt<<<dim3(32, 32), tb, 0, stream>>>(Wk, wk_t, 1024, 1024);
  transpose_cvt<<<dim3(32, 32), tb, 0, stream>>>(Wv, wv_t, 1024, 1024);
  transpose_cvt<<<dim3(32, 32), tb, 0, stream>>>(Wo, wo_t, 1024, 1024);
  transpose_cvt<<<dim3(128, 32), tb, 0, stream>>>(W1, w1_t, 1024, 4096);
  transpose_cvt<<<dim3(32, 128), tb, 0, stream>>>(W2, w2_t, 4096, 1024);
  cvt_modal<<<16384, 256, 0, stream>>>(src, mod1, mod2);

  auto phase = [&](const uint16_t* qsrc, const uint16_t* kvsrc, int soff,
                   float* out_f, uint16_t* out_bf) {
    // projections
    gemm_bt<0, false, false><<<1024, 256, 0, stream>>>(qsrc, wq_t, bq, nullptr, QB,
                                                       16384, 1024, 1024, 8, 0);
    gemm_bt<0, false, false><<<1024, 256, 0, stream>>>(kvsrc, wk_t, bk, nullptr, KB,
                                                       16384, 1024, 1024, 8, 0);
    gemm_bt<0, false, false><<<1024, 256, 0, stream>>>(kvsrc, wv_t, bv, nullptr, VB,
                                                       16384, 1024, 1024, 8, 0);
    attn_kern<<<2048, 256, 0, stream>>>(QB, KB, VB, ATT);
    // out-proj + residual from src slice
    gemm_bt<2, false, true><<<1024, 256, 0, stream>>>(ATT, wo_t, bo, src, XA,
                                                      16384, 1024, 1024, 8, soff);
    ln2d<<<128, 256, 0, stream>>>(XA, g1, be1, YF, 131072, YBF);
    // FFN
    gemm_bt<0, true, false><<<4096, 256, 0, stream>>>(YBF, w1_t, b1, nullptr, Hbf,
                                                      16384, 4096, 1024, 32, 0);
    gemm_bt<1, false, true><<<1024, 256, 0, stream>>>(Hbf, w2_t, b2, YF, XA,
                                                      16384, 1024, 4096, 8, 0);
    ln2d<<<128, 256, 0, stream>>>(XA, g2, be2, out_f, 262144, out_bf);
  };

  phase(mod1, mod2, 0, dout, m1bf);
  phase(mod2, m1bf, 128, dout + 131072, nullptr);

  (void)in_sizes; (void)n_in; (void)out_size; (void)ws_size;
}

// Round 2
// 1726.417 us; speedup vs baseline: 1.0972x; 1.0972x over previous
//
#include <hip/hip_runtime.h>
#include <stdint.h>

#define DEV __device__ __forceinline__

typedef __bf16 bf16x8 __attribute__((ext_vector_type(8)));
typedef float  f32x4  __attribute__((ext_vector_type(4)));

struct alignas(8) U16x4 { uint16_t x, y, z, w; };

DEV uint16_t f2bf(float f) {
  union { float f; uint32_t u; } v; v.f = f;
  uint32_t r = v.u + 0x7fffu + ((v.u >> 16) & 1u);
  return (uint16_t)(r >> 16);
}

DEV void gload16(const void* g, void* l) {
  __builtin_amdgcn_global_load_lds((__attribute__((address_space(1))) void*)(g),
                                   (__attribute__((address_space(3))) void*)(l),
                                   16, 0, 0);
}

// ---------------------------------------------------------------------------
// Weight transpose + f32->bf16:  in [R][C] f32  ->  out [C][R] bf16
// ---------------------------------------------------------------------------
__global__ __launch_bounds__(1024) void transpose_cvt(
    const float* __restrict__ in, uint16_t* __restrict__ out, int R, int C) {
  __shared__ float tile[32][33];
  const int tx = threadIdx.x, ty = threadIdx.y;
  const int r = blockIdx.y * 32 + ty, c = blockIdx.x * 32 + tx;
  tile[ty][tx] = in[(size_t)r * C + c];
  __syncthreads();
  const int oc = blockIdx.x * 32 + ty;   // output row (former column)
  const int orr = blockIdx.y * 32 + tx;  // output col (former row)
  out[(size_t)oc * R + orr] = f2bf(tile[tx][ty]);
}

// ---------------------------------------------------------------------------
// Slice src into modal1/modal2 token-major bf16 [16384][1024]
// ---------------------------------------------------------------------------
__global__ __launch_bounds__(256) void cvt_modal(
    const float* __restrict__ src, uint16_t* __restrict__ m1, uint16_t* __restrict__ m2) {
  const int idx = blockIdx.x * 256 + threadIdx.x;  // float4 group
  const int E = idx * 4;
  const int t = E >> 10, dd = E & 1023;
  const size_t s1 = ((size_t)(t >> 7) * 256 + (t & 127)) * 1024 + dd;
  float4 a = *(const float4*)&src[s1];
  float4 b = *(const float4*)&src[s1 + 131072];  // s + 128 rows
  U16x4 pa{f2bf(a.x), f2bf(a.y), f2bf(a.z), f2bf(a.w)};
  U16x4 pb{f2bf(b.x), f2bf(b.y), f2bf(b.z), f2bf(b.w)};
  *(U16x4*)&m1[E] = pa;
  *(U16x4*)&m2[E] = pb;
}

// ---------------------------------------------------------------------------
// GEMM 256x256 tile, BK=32, 8 waves (2Mx4N), 4-deep LDS pipeline, counted
// vmcnt, chunk-XOR swizzle, XCD-aware bn-major block order.
// C[M][N] = A[M][K] @ Bt[N][K]^T + bias (+relu) (+resid)
// RESID: 0 none, 1 plain f32 [M][1024], 2 strided src slice (soff)
// Requires M%256==0, N%256==0, K%32==0, K>=64, grid%8==0.
// ---------------------------------------------------------------------------
template <int RESID, bool RELU, bool OUTF32>
__global__ __launch_bounds__(512, 2) void gemm256(
    const uint16_t* __restrict__ A, const uint16_t* __restrict__ Bt,
    const float* __restrict__ bias, const float* __restrict__ resid,
    void* __restrict__ outp, int N, int K, int nbm, int soff) {
  __shared__ __align__(16) uint16_t lds[65536];  // 128 KiB: A 4x8192, B 4x8192 elems

  // ---- block swizzle: XCD-bijective, bn-major within XCD ----
  const int nwg = gridDim.x;
  const int s = (blockIdx.x & 7) * (nwg >> 3) + (blockIdx.x >> 3);
  const int bn = s / nbm, bm = s % nbm;
  const int brow = bm << 8, bcol = bn << 8;

  const int tid = threadIdx.x;
  const int w = tid >> 6, lane = tid & 63, l15 = lane & 15, lhi = lane >> 4;
  const int wm = w >> 2, wn = w & 3;

  // ---- staging addressing (linear LDS dest, inverse-swizzled global src) ----
  const int srow = w * 16 + (lane >> 2);              // 0..127 within half
  const int cswz = (lane & 3) ^ ((lane >> 3) & 3);    // global chunk fetched
  const uint16_t* gA0 = A + (size_t)(brow + srow) * K + cswz * 8;
  const uint16_t* gA1 = A + (size_t)(brow + 128 + srow) * K + cswz * 8;
  const uint16_t* gB0 = Bt + (size_t)(bcol + srow) * K + cswz * 8;
  const uint16_t* gB1 = Bt + (size_t)(bcol + 128 + srow) * K + cswz * 8;
  const int wS = w * 512;  // wave's element offset within a 4096-elem half

  // ---- read addressing (swizzled chunk position) ----
  const int p = lhi ^ ((l15 >> 1) & 3);
  const int aoff = (wm * 128 + l15) * 32 + p * 8;
  const int boff = (wn * 64 + l15) * 32 + p * 8;

  f32x4 acc[8][4];
  const f32x4 z = {0.f, 0.f, 0.f, 0.f};
#pragma unroll
  for (int m = 0; m < 8; ++m)
#pragma unroll
    for (int n = 0; n < 4; ++n) acc[m][n] = z;

  const int nt = K >> 5;

  // ---- prologue: stage tiles 0 (buf0) and 1 (buf1) ----
  gload16(gA0, &lds[wS]);
  gload16(gA1, &lds[4096 + wS]);
  gload16(gB0, &lds[32768 + wS]);
  gload16(gB1, &lds[32768 + 4096 + wS]);
  gload16(gA0 + 32, &lds[8192 + wS]);
  gload16(gA1 + 32, &lds[8192 + 4096 + wS]);
  gload16(gB0 + 32, &lds[32768 + 8192 + wS]);
  gload16(gB1 + 32, &lds[32768 + 8192 + 4096 + wS]);
  asm volatile("s_waitcnt vmcnt(4)" ::: "memory");  // tile 0 landed
  __builtin_amdgcn_s_barrier();
  __builtin_amdgcn_sched_barrier(0);

  for (int t = 0; t < nt; ++t) {
    const int abase = (t & 3) * 8192;
    const int bbase = 32768 + (t & 3) * 8192;
    const bool st = (t + 2 < nt);
    const int kn = (t + 2) << 5;
    const int sb = ((t + 2) & 3) * 8192;
    bf16x8 afr[4], bfr[4];

    // ================= phase A =================
#pragma unroll
    for (int n = 0; n < 4; ++n) bfr[n] = *(const bf16x8*)&lds[bbase + boff + n * 512];
#pragma unroll
    for (int m = 0; m < 4; ++m) afr[m] = *(const bf16x8*)&lds[abase + aoff + m * 512];
    if (st) {
      gload16(gA0 + kn, &lds[sb + wS]);
      gload16(gA1 + kn, &lds[sb + 4096 + wS]);
    }
    __builtin_amdgcn_s_barrier();
    asm volatile("s_waitcnt lgkmcnt(0)" ::: "memory");
    __builtin_amdgcn_sched_barrier(0);
    __builtin_amdgcn_s_setprio(1);
#pragma unroll
    for (int m = 0; m < 4; ++m)
#pragma unroll
      for (int n = 0; n < 4; ++n)
        acc[m][n] = __builtin_amdgcn_mfma_f32_16x16x32_bf16(afr[m], bfr[n], acc[m][n], 0, 0, 0);
    __builtin_amdgcn_s_setprio(0);
    __builtin_amdgcn_sched_barrier(0);
    __builtin_amdgcn_s_barrier();
    __builtin_amdgcn_sched_barrier(0);

    // ================= phase B =================
#pragma unroll
    for (int m = 0; m < 4; ++m) afr[m] = *(const bf16x8*)&lds[abase + aoff + (m + 4) * 512];
    if (st) {
      gload16(gB0 + kn, &lds[32768 + sb + wS]);
      gload16(gB1 + kn, &lds[32768 + sb + 4096 + wS]);
    }
    __builtin_amdgcn_s_barrier();
    asm volatile("s_waitcnt lgkmcnt(0)" ::: "memory");
    __builtin_amdgcn_sched_barrier(0);
    __builtin_amdgcn_s_setprio(1);
#pragma unroll
    for (int m = 0; m < 4; ++m)
#pragma unroll
      for (int n = 0; n < 4; ++n)
        acc[m + 4][n] = __builtin_amdgcn_mfma_f32_16x16x32_bf16(afr[m], bfr[n], acc[m + 4][n], 0, 0, 0);
    __builtin_amdgcn_s_setprio(0);
    __builtin_amdgcn_sched_barrier(0);
    if (st) asm volatile("s_waitcnt vmcnt(4)" ::: "memory");  // tile t+1 landed
    else    asm volatile("s_waitcnt vmcnt(0)" ::: "memory");  // epilogue drain
    __builtin_amdgcn_s_barrier();
    __builtin_amdgcn_sched_barrier(0);
  }

  // ---- epilogue ----
#pragma unroll
  for (int n = 0; n < 4; ++n) {
    const int col = bcol + wn * 64 + n * 16 + l15;
    const float bs = bias[col];
#pragma unroll
    for (int m = 0; m < 8; ++m) {
#pragma unroll
      for (int r = 0; r < 4; ++r) {
        const int row = brow + wm * 128 + m * 16 + lhi * 4 + r;
        float v = acc[m][n][r] + bs;
        if (RELU) v = fmaxf(v, 0.f);
        if (RESID == 1) v += resid[(size_t)row * 1024 + col];
        if (RESID == 2)
          v += resid[((size_t)(row >> 7) * 256 + soff + (row & 127)) * 1024 + col];
        if (OUTF32)
          ((float*)outp)[(size_t)row * N + col] = v;
        else
          ((uint16_t*)outp)[(size_t)row * N + col] = f2bf(v);
      }
    }
  }
}

// ---------------------------------------------------------------------------
// Attention core: one block per (b,h). S=128, dh=64. Q,K,V bf16 [t][1024].
// ---------------------------------------------------------------------------
__global__ __launch_bounds__(256) void attn_kern(
    const uint16_t* __restrict__ Q, const uint16_t* __restrict__ Kv,
    const uint16_t* __restrict__ V, uint16_t* __restrict__ O) {
  __shared__ uint16_t sm[24576];  // 48 KB: [Q 16K | K 16K | Vt 16K]; P aliases Q+K
  uint16_t* sQ = sm;
  uint16_t* sK = sm + 8192;
  uint16_t* sVt = sm + 16384;
  uint16_t* sP = sm;  // 128x128 bf16 = 32KB, reuses Q+K after barrier
  const int bh = blockIdx.x, b = bh >> 4, h = bh & 15;
  const int tid = threadIdx.x, w = tid >> 6, lane = tid & 63, l15 = lane & 15, lhi = lane >> 4;
  const size_t base = (size_t)b * 131072 + h * 64;

  for (int i = 0; i < 4; ++i) {
    const int gidx = i * 256 + tid;
    const int row = gidx >> 3, co = (gidx & 7) * 8;
    *(uint4*)&sQ[row * 64 + co] = *(const uint4*)&Q[base + (size_t)row * 1024 + co];
    *(uint4*)&sK[row * 64 + co] = *(const uint4*)&Kv[base + (size_t)row * 1024 + co];
  }
  {
    const int r = tid >> 1, cb = (tid & 1) * 32;
    for (int jj = 0; jj < 4; ++jj) {
      uint4 vv = *(const uint4*)&V[base + (size_t)r * 1024 + cb + jj * 8];
      const uint16_t* e = (const uint16_t*)&vv;
      for (int j = 0; j < 8; ++j) sVt[(cb + jj * 8 + j) * 128 + r] = e[j];
    }
  }
  __syncthreads();

  f32x4 s[2][8];
  const f32x4 z = {0.f, 0.f, 0.f, 0.f};
  for (int m = 0; m < 2; ++m)
    for (int n = 0; n < 8; ++n) s[m][n] = z;
#pragma unroll
  for (int kk = 0; kk < 2; ++kk) {
    bf16x8 aq[2];
#pragma unroll
    for (int m = 0; m < 2; ++m)
      aq[m] = *(const bf16x8*)&sQ[(w * 32 + m * 16 + l15) * 64 + kk * 32 + lhi * 8];
#pragma unroll
    for (int n = 0; n < 8; ++n) {
      bf16x8 bk = *(const bf16x8*)&sK[(n * 16 + l15) * 64 + kk * 32 + lhi * 8];
#pragma unroll
      for (int m = 0; m < 2; ++m)
        s[m][n] = __builtin_amdgcn_mfma_f32_16x16x32_bf16(aq[m], bk, s[m][n], 0, 0, 0);
    }
  }

  for (int m = 0; m < 2; ++m) {
    float mx[4], sum[4];
#pragma unroll
    for (int r = 0; r < 4; ++r) {
      float v = s[m][0][r];
      for (int n = 1; n < 8; ++n) v = fmaxf(v, s[m][n][r]);
      for (int msk = 1; msk < 16; msk <<= 1) v = fmaxf(v, __shfl_xor(v, msk, 64));
      mx[r] = v;
      sum[r] = 0.f;
    }
    for (int n = 0; n < 8; ++n)
      for (int r = 0; r < 4; ++r) {
        float e = __expf((s[m][n][r] - mx[r]) * 0.125f);
        s[m][n][r] = e;
        sum[r] += e;
      }
#pragma unroll
    for (int r = 0; r < 4; ++r) {
      float t = sum[r];
      for (int msk = 1; msk < 16; msk <<= 1) t += __shfl_xor(t, msk, 64);
      sum[r] = 1.f / t;
    }
    for (int n = 0; n < 8; ++n)
      for (int r = 0; r < 4; ++r) s[m][n][r] *= sum[r];
  }
  __syncthreads();

  for (int m = 0; m < 2; ++m)
    for (int n = 0; n < 8; ++n)
      for (int r = 0; r < 4; ++r)
        sP[(w * 32 + m * 16 + lhi * 4 + r) * 128 + n * 16 + l15] = f2bf(s[m][n][r]);
  __syncthreads();

  f32x4 o[2][4];
  for (int m = 0; m < 2; ++m)
    for (int n = 0; n < 4; ++n) o[m][n] = z;
#pragma unroll
  for (int kk = 0; kk < 4; ++kk) {
    bf16x8 ap[2];
#pragma unroll
    for (int m = 0; m < 2; ++m)
      ap[m] = *(const bf16x8*)&sP[(w * 32 + m * 16 + l15) * 128 + kk * 32 + lhi * 8];
#pragma unroll
    for (int n = 0; n < 4; ++n) {
      bf16x8 bv = *(const bf16x8*)&sVt[(n * 16 + l15) * 128 + kk * 32 + lhi * 8];
#pragma unroll
      for (int m = 0; m < 2; ++m)
        o[m][n] = __builtin_amdgcn_mfma_f32_16x16x32_bf16(ap[m], bv, o[m][n], 0, 0, 0);
    }
  }
  for (int m = 0; m < 2; ++m)
    for (int n = 0; n < 4; ++n)
      for (int r = 0; r < 4; ++r) {
        const int q = w * 32 + m * 16 + lhi * 4 + r, c = n * 16 + l15;
        O[base + (size_t)q * 1024 + c] = f2bf(o[m][n][r]);
      }
}

// ---------------------------------------------------------------------------
// LN2D: per-batch-element layernorm over 128x1024. 512 threads.
// ---------------------------------------------------------------------------
__global__ __launch_bounds__(512) void ln2d(
    const float* __restrict__ x, const float* __restrict__ g, const float* __restrict__ bet,
    float* __restrict__ outf, int bstride, uint16_t* __restrict__ outbf) {
  const int b = blockIdx.x, tid = threadIdx.x;
  const float4* xb = (const float4*)(x + (size_t)b * 131072);
  float s = 0.f, ss = 0.f;
  for (int i = tid; i < 32768; i += 512) {
    float4 v = xb[i];
    s += (v.x + v.y) + (v.z + v.w);
    ss += (v.x * v.x + v.y * v.y) + (v.z * v.z + v.w * v.w);
  }
#pragma unroll
  for (int m = 1; m < 64; m <<= 1) {
    s += __shfl_xor(s, m, 64);
    ss += __shfl_xor(ss, m, 64);
  }
  __shared__ float red[16];
  __shared__ float stats[2];
  const int w = tid >> 6;
  if ((tid & 63) == 0) {
    red[w] = s;
    red[8 + w] = ss;
  }
  __syncthreads();
  if (tid == 0) {
    float S = 0.f, SS = 0.f;
    for (int i = 0; i < 8; ++i) { S += red[i]; SS += red[8 + i]; }
    const float mu = S * (1.f / 131072.f);
    const float var = SS * (1.f / 131072.f) - mu * mu;
    stats[0] = mu;
    stats[1] = rsqrtf(var + 1e-5f);
  }
  __syncthreads();
  const float mu = stats[0], rs = stats[1];
  float* of = outf + (size_t)b * (size_t)bstride;
  uint16_t* ob = outbf ? outbf + (size_t)b * 131072 : nullptr;
  const float4* g4 = (const float4*)g;
  const float4* b4 = (const float4*)bet;
  for (int i = tid; i < 32768; i += 512) {
    float4 v = xb[i], gg = g4[i], bb = b4[i];
    float4 o;
    o.x = (v.x - mu) * rs * gg.x + bb.x;
    o.y = (v.y - mu) * rs * gg.y + bb.y;
    o.z = (v.z - mu) * rs * gg.z + bb.z;
    o.w = (v.w - mu) * rs * gg.w + bb.w;
    *(float4*)&of[(size_t)i * 4] = o;
    if (ob) {
      U16x4 u{f2bf(o.x), f2bf(o.y), f2bf(o.z), f2bf(o.w)};
      *(U16x4*)&ob[(size_t)i * 4] = u;
    }
  }
}

// ---------------------------------------------------------------------------
extern "C" void kernel_launch(void* const* d_in, const int* in_sizes, int n_in,
                              void* d_out, int out_size, void* d_ws, size_t ws_size,
                              hipStream_t stream) {
  const float* src = (const float*)d_in[0];
  const float* Wq = (const float*)d_in[1];
  const float* bq = (const float*)d_in[2];
  const float* Wk = (const float*)d_in[3];
  const float* bk = (const float*)d_in[4];
  const float* Wv = (const float*)d_in[5];
  const float* bv = (const float*)d_in[6];
  const float* Wo = (const float*)d_in[7];
  const float* bo = (const float*)d_in[8];
  const float* W1 = (const float*)d_in[9];
  const float* b1 = (const float*)d_in[10];
  const float* W2 = (const float*)d_in[11];
  const float* b2 = (const float*)d_in[12];
  const float* g1 = (const float*)d_in[13];
  const float* be1 = (const float*)d_in[14];
  const float* g2 = (const float*)d_in[15];
  const float* be2 = (const float*)d_in[16];
  float* dout = (float*)d_out;
  char* ws = (char*)d_ws;

  const size_t MB = 1024 * 1024;
  uint16_t* wq_t = (uint16_t*)(ws + 0 * MB);
  uint16_t* wk_t = (uint16_t*)(ws + 2 * MB);
  uint16_t* wv_t = (uint16_t*)(ws + 4 * MB);
  uint16_t* wo_t = (uint16_t*)(ws + 6 * MB);
  uint16_t* w1_t = (uint16_t*)(ws + 8 * MB);   // [4096][1024]
  uint16_t* w2_t = (uint16_t*)(ws + 16 * MB);  // [1024][4096]
  uint16_t* m1bf = (uint16_t*)(ws + 24 * MB);  // final m1 bf16 (phase-B KV src)
  uint16_t* mod2 = (uint16_t*)(ws + 56 * MB);
  uint16_t* QB = (uint16_t*)(ws + 88 * MB);
  uint16_t* KB = (uint16_t*)(ws + 120 * MB);
  uint16_t* VB = (uint16_t*)(ws + 152 * MB);
  uint16_t* ATT = (uint16_t*)(ws + 184 * MB);
  uint16_t* Hbf = QB;  // 128 MB FFN hidden aliases QB..ATT (dead by then)
  uint16_t* mod1 = (uint16_t*)(ws + 216 * MB);
  float* XA = (float*)(ws + 248 * MB);
  float* YF = (float*)(ws + 312 * MB);
  uint16_t* YBF = (uint16_t*)(ws + 376 * MB);
  // total: 408 MB

  dim3 tb(32, 32);
  transpose_cvt<<<dim3(32, 32), tb, 0, stream>>>(Wq, wq_t, 1024, 1024);
  transpose_cvt<<<dim3(32, 32), tb, 0, stream>>>(Wk, wk_t, 1024, 1024);
  transpose_cvt<<<dim3(32, 32), tb, 0, stream>>>(Wv, wv_t, 1024, 1024);
  transpose_cvt<<<dim3(32, 32), tb, 0, stream>>>(Wo, wo_t, 1024, 1024);
  transpose_cvt<<<dim3(128, 32), tb, 0, stream>>>(W1, w1_t, 1024, 4096);
  transpose_cvt<<<dim3(32, 128), tb, 0, stream>>>(W2, w2_t, 4096, 1024);
  cvt_modal<<<16384, 256, 0, stream>>>(src, mod1, mod2);

  auto phase = [&](const uint16_t* qsrc, const uint16_t* kvsrc, int soff,
                   float* out_f, uint16_t* out_bf) {
    // projections: M=16384, N=1024, K=1024 -> 256 blocks
    gemm256<0, false, false><<<256, 512, 0, stream>>>(qsrc, wq_t, bq, nullptr, QB,
                                                      1024, 1024, 64, 0);
    gemm256<0, false, false><<<256, 512, 0, stream>>>(kvsrc, wk_t, bk, nullptr, KB,
                                                      1024, 1024, 64, 0);
    gemm256<0, false, false><<<256, 512, 0, stream>>>(kvsrc, wv_t, bv, nullptr, VB,
                                                      1024, 1024, 64, 0);
    attn_kern<<<2048, 256, 0, stream>>>(QB, KB, VB, ATT);
    // out-proj + residual from src slice
    gemm256<2, false, true><<<256, 512, 0, stream>>>(ATT, wo_t, bo, src, XA,
                                                     1024, 1024, 64, soff);
    ln2d<<<128, 512, 0, stream>>>(XA, g1, be1, YF, 131072, YBF);
    // FFN: 16384x4096x1024 then 16384x1024x4096
    gemm256<0, true, false><<<1024, 512, 0, stream>>>(YBF, w1_t, b1, nullptr, Hbf,
                                                      4096, 1024, 64, 0);
    gemm256<1, false, true><<<256, 512, 0, stream>>>(Hbf, w2_t, b2, YF, XA,
                                                     1024, 4096, 64, 0);
    ln2d<<<128, 512, 0, stream>>>(XA, g2, be2, out_f, 262144, out_bf);
  };

  phase(mod1, mod2, 0, dout, m1bf);
  phase(mod2, m1bf, 128, dout + 131072, nullptr);

  (void)in_sizes; (void)n_in; (void)out_size; (void)ws_size;
}

// Round 3
// 1613.729 us; speedup vs baseline: 1.1738x; 1.0698x over previous
//
#include <hip/hip_runtime.h>
#include <stdint.h>

#define DEV __device__ __forceinline__

typedef __bf16 bf16x8 __attribute__((ext_vector_type(8)));
typedef float  f32x4  __attribute__((ext_vector_type(4)));

struct alignas(8) U16x4 { uint16_t x, y, z, w; };

DEV uint16_t f2bf(float f) {
  union { float f; uint32_t u; } v; v.f = f;
  uint32_t r = v.u + 0x7fffu + ((v.u >> 16) & 1u);
  return (uint16_t)(r >> 16);
}

DEV void gload16(const void* g, void* l) {
  __builtin_amdgcn_global_load_lds((__attribute__((address_space(1))) void*)(g),
                                   (__attribute__((address_space(3))) void*)(l),
                                   16, 0, 0);
}

// ---------------------------------------------------------------------------
// Weight transpose + f32->bf16:  in [R][C] f32  ->  out [C][R] bf16
// ---------------------------------------------------------------------------
__global__ __launch_bounds__(1024) void transpose_cvt(
    const float* __restrict__ in, uint16_t* __restrict__ out, int R, int C) {
  __shared__ float tile[32][33];
  const int tx = threadIdx.x, ty = threadIdx.y;
  const int r = blockIdx.y * 32 + ty, c = blockIdx.x * 32 + tx;
  tile[ty][tx] = in[(size_t)r * C + c];
  __syncthreads();
  const int oc = blockIdx.x * 32 + ty;   // output row (former column)
  const int orr = blockIdx.y * 32 + tx;  // output col (former row)
  out[(size_t)oc * R + orr] = f2bf(tile[tx][ty]);
}

// ---------------------------------------------------------------------------
// Slice src into modal1/modal2 token-major bf16 [16384][1024]
// ---------------------------------------------------------------------------
__global__ __launch_bounds__(256) void cvt_modal(
    const float* __restrict__ src, uint16_t* __restrict__ m1, uint16_t* __restrict__ m2) {
  const int idx = blockIdx.x * 256 + threadIdx.x;  // float4 group
  const int E = idx * 4;
  const int t = E >> 10, dd = E & 1023;
  const size_t s1 = ((size_t)(t >> 7) * 256 + (t & 127)) * 1024 + dd;
  float4 a = *(const float4*)&src[s1];
  float4 b = *(const float4*)&src[s1 + 131072];  // s + 128 rows
  U16x4 pa{f2bf(a.x), f2bf(a.y), f2bf(a.z), f2bf(a.w)};
  U16x4 pb{f2bf(b.x), f2bf(b.y), f2bf(b.z), f2bf(b.w)};
  *(U16x4*)&m1[E] = pa;
  *(U16x4*)&m2[E] = pb;
}

// ---------------------------------------------------------------------------
// GEMM 256x256 tile, BK=32, 8 waves (2Mx4N), 4-buffer 3-deep LDS pipeline,
// counted vmcnt, chunk-XOR swizzle, XCD-contiguous + bm-major block order
// (same-A-panel blocks are concurrent neighbors on one XCD -> A hits L2).
// C[M][N] = A[M][K] @ Bt[N][K]^T + bias (+relu) (+resid)
// RESID: 0 none, 1 plain f32 [M][1024], 2 strided src slice (soff)
// Requires M%256==0, N%256==0, K%32==0, K>=128, grid%8==0.
// ---------------------------------------------------------------------------
#define TILE(T, ST, WAITSTR)                                                    \
  {                                                                             \
    const int abase = ((T) & 3) * 8192;                                         \
    const int bbase = 32768 + ((T) & 3) * 8192;                                 \
    const int kn = ((T) + 3) << 5;                                              \
    const int sb = (((T) + 3) & 3) * 8192;                                      \
    bf16x8 afr[4], bfr[4];                                                      \
    _Pragma("unroll") for (int n = 0; n < 4; ++n)                               \
        bfr[n] = *(const bf16x8*)&lds[bbase + boff + n * 512];                  \
    _Pragma("unroll") for (int m = 0; m < 4; ++m)                               \
        afr[m] = *(const bf16x8*)&lds[abase + aoff + m * 512];                  \
    if (ST) {                                                                   \
      gload16(gA0 + kn, &lds[sb + wS]);                                         \
      gload16(gA1 + kn, &lds[sb + 4096 + wS]);                                  \
    }                                                                           \
    __builtin_amdgcn_s_barrier();                                               \
    asm volatile("s_waitcnt lgkmcnt(0)" ::: "memory");                          \
    __builtin_amdgcn_sched_barrier(0);                                          \
    __builtin_amdgcn_s_setprio(1);                                              \
    _Pragma("unroll") for (int m = 0; m < 4; ++m)                               \
        _Pragma("unroll") for (int n = 0; n < 4; ++n)                           \
        acc[m][n] = __builtin_amdgcn_mfma_f32_16x16x32_bf16(afr[m], bfr[n],     \
                                                            acc[m][n], 0, 0, 0);\
    __builtin_amdgcn_s_setprio(0);                                              \
    __builtin_amdgcn_sched_barrier(0);                                          \
    __builtin_amdgcn_s_barrier();                                               \
    __builtin_amdgcn_sched_barrier(0);                                          \
    _Pragma("unroll") for (int m = 0; m < 4; ++m)                               \
        afr[m] = *(const bf16x8*)&lds[abase + aoff + (m + 4) * 512];            \
    if (ST) {                                                                   \
      gload16(gB0 + kn, &lds[32768 + sb + wS]);                                 \
      gload16(gB1 + kn, &lds[32768 + sb + 4096 + wS]);                          \
    }                                                                           \
    __builtin_amdgcn_s_barrier();                                               \
    asm volatile("s_waitcnt lgkmcnt(0)" ::: "memory");                          \
    __builtin_amdgcn_sched_barrier(0);                                          \
    __builtin_amdgcn_s_setprio(1);                                              \
    _Pragma("unroll") for (int m = 0; m < 4; ++m)                               \
        _Pragma("unroll") for (int n = 0; n < 4; ++n)                           \
        acc[m + 4][n] = __builtin_amdgcn_mfma_f32_16x16x32_bf16(                \
            afr[m], bfr[n], acc[m + 4][n], 0, 0, 0);                            \
    __builtin_amdgcn_s_setprio(0);                                              \
    __builtin_amdgcn_sched_barrier(0);                                          \
    asm volatile(WAITSTR ::: "memory");                                         \
    __builtin_amdgcn_s_barrier();                                               \
    __builtin_amdgcn_sched_barrier(0);                                          \
  }

template <int RESID, bool RELU, bool OUTF32>
__global__ __launch_bounds__(512, 2) void gemm256(
    const uint16_t* __restrict__ A, const uint16_t* __restrict__ Bt,
    const float* __restrict__ bias, const float* __restrict__ resid,
    void* __restrict__ outp, int N, int K, int nbn, int soff) {
  __shared__ __align__(16) uint16_t lds[65536];  // 128 KiB: A 4x8192, B 4x8192 elems

  // ---- block swizzle: XCD-contiguous s, bm-major decode ----
  const int nwg = gridDim.x;
  const int s = (blockIdx.x & 7) * (nwg >> 3) + (blockIdx.x >> 3);
  const int bm = s / nbn, bn = s % nbn;
  const int brow = bm << 8, bcol = bn << 8;

  const int tid = threadIdx.x;
  const int w = tid >> 6, lane = tid & 63, l15 = lane & 15, lhi = lane >> 4;
  const int wm = w >> 2, wn = w & 3;

  // ---- staging addressing (linear LDS dest, inverse-swizzled global src) ----
  const int srow = w * 16 + (lane >> 2);              // 0..127 within half
  const int cswz = (lane & 3) ^ ((lane >> 3) & 3);    // global chunk fetched
  const uint16_t* gA0 = A + (size_t)(brow + srow) * K + cswz * 8;
  const uint16_t* gA1 = A + (size_t)(brow + 128 + srow) * K + cswz * 8;
  const uint16_t* gB0 = Bt + (size_t)(bcol + srow) * K + cswz * 8;
  const uint16_t* gB1 = Bt + (size_t)(bcol + 128 + srow) * K + cswz * 8;
  const int wS = w * 512;  // wave's element offset within a 4096-elem half

  // ---- read addressing (swizzled chunk position) ----
  const int p = lhi ^ ((l15 >> 1) & 3);
  const int aoff = (wm * 128 + l15) * 32 + p * 8;
  const int boff = (wn * 64 + l15) * 32 + p * 8;

  f32x4 acc[8][4];
  const f32x4 z = {0.f, 0.f, 0.f, 0.f};
#pragma unroll
  for (int m = 0; m < 8; ++m)
#pragma unroll
    for (int n = 0; n < 4; ++n) acc[m][n] = z;

  const int nt = K >> 5;

  // ---- prologue: stage tiles 0,1,2 ----
#pragma unroll
  for (int pt = 0; pt < 3; ++pt) {
    const int sb = pt * 8192, kk = pt << 5;
    gload16(gA0 + kk, &lds[sb + wS]);
    gload16(gA1 + kk, &lds[sb + 4096 + wS]);
    gload16(gB0 + kk, &lds[32768 + sb + wS]);
    gload16(gB1 + kk, &lds[32768 + sb + 4096 + wS]);
  }
  asm volatile("s_waitcnt vmcnt(8)" ::: "memory");  // tile 0 landed
  __builtin_amdgcn_s_barrier();
  __builtin_amdgcn_sched_barrier(0);

  int t = 0;
  for (; t < nt - 3; ++t) TILE(t, true, "s_waitcnt vmcnt(8)");
  TILE(t, false, "s_waitcnt vmcnt(4)");
  ++t;
  TILE(t, false, "s_waitcnt vmcnt(0)");
  ++t;
  TILE(t, false, "");

  // ---- epilogue ----
#pragma unroll
  for (int n = 0; n < 4; ++n) {
    const int col = bcol + wn * 64 + n * 16 + l15;
    const float bs = bias[col];
#pragma unroll
    for (int m = 0; m < 8; ++m) {
#pragma unroll
      for (int r = 0; r < 4; ++r) {
        const int row = brow + wm * 128 + m * 16 + lhi * 4 + r;
        float v = acc[m][n][r] + bs;
        if (RELU) v = fmaxf(v, 0.f);
        if (RESID == 1) v += resid[(size_t)row * 1024 + col];
        if (RESID == 2)
          v += resid[((size_t)(row >> 7) * 256 + soff + (row & 127)) * 1024 + col];
        if (OUTF32)
          ((float*)outp)[(size_t)row * N + col] = v;
        else
          ((uint16_t*)outp)[(size_t)row * N + col] = f2bf(v);
      }
    }
  }
}

// ---------------------------------------------------------------------------
// Attention core: one block per (b,h). S=128, dh=64. Q,K,V bf16 [t][1024].
// ---------------------------------------------------------------------------
__global__ __launch_bounds__(256) void attn_kern(
    const uint16_t* __restrict__ Q, const uint16_t* __restrict__ Kv,
    const uint16_t* __restrict__ V, uint16_t* __restrict__ O) {
  __shared__ uint16_t sm[24576];  // 48 KB: [Q 16K | K 16K | Vt 16K]; P aliases Q+K
  uint16_t* sQ = sm;
  uint16_t* sK = sm + 8192;
  uint16_t* sVt = sm + 16384;
  uint16_t* sP = sm;  // 128x128 bf16 = 32KB, reuses Q+K after barrier
  const int bh = blockIdx.x, b = bh >> 4, h = bh & 15;
  const int tid = threadIdx.x, w = tid >> 6, lane = tid & 63, l15 = lane & 15, lhi = lane >> 4;
  const size_t base = (size_t)b * 131072 + h * 64;

  for (int i = 0; i < 4; ++i) {
    const int gidx = i * 256 + tid;
    const int row = gidx >> 3, co = (gidx & 7) * 8;
    *(uint4*)&sQ[row * 64 + co] = *(const uint4*)&Q[base + (size_t)row * 1024 + co];
    *(uint4*)&sK[row * 64 + co] = *(const uint4*)&Kv[base + (size_t)row * 1024 + co];
  }
  {
    const int r = tid >> 1, cb = (tid & 1) * 32;
    for (int jj = 0; jj < 4; ++jj) {
      uint4 vv = *(const uint4*)&V[base + (size_t)r * 1024 + cb + jj * 8];
      const uint16_t* e = (const uint16_t*)&vv;
      for (int j = 0; j < 8; ++j) sVt[(cb + jj * 8 + j) * 128 + r] = e[j];
    }
  }
  __syncthreads();

  f32x4 s[2][8];
  const f32x4 z = {0.f, 0.f, 0.f, 0.f};
  for (int m = 0; m < 2; ++m)
    for (int n = 0; n < 8; ++n) s[m][n] = z;
#pragma unroll
  for (int kk = 0; kk < 2; ++kk) {
    bf16x8 aq[2];
#pragma unroll
    for (int m = 0; m < 2; ++m)
      aq[m] = *(const bf16x8*)&sQ[(w * 32 + m * 16 + l15) * 64 + kk * 32 + lhi * 8];
#pragma unroll
    for (int n = 0; n < 8; ++n) {
      bf16x8 bk = *(const bf16x8*)&sK[(n * 16 + l15) * 64 + kk * 32 + lhi * 8];
#pragma unroll
      for (int m = 0; m < 2; ++m)
        s[m][n] = __builtin_amdgcn_mfma_f32_16x16x32_bf16(aq[m], bk, s[m][n], 0, 0, 0);
    }
  }

  for (int m = 0; m < 2; ++m) {
    float mx[4], sum[4];
#pragma unroll
    for (int r = 0; r < 4; ++r) {
      float v = s[m][0][r];
      for (int n = 1; n < 8; ++n) v = fmaxf(v, s[m][n][r]);
      for (int msk = 1; msk < 16; msk <<= 1) v = fmaxf(v, __shfl_xor(v, msk, 64));
      mx[r] = v;
      sum[r] = 0.f;
    }
    for (int n = 0; n < 8; ++n)
      for (int r = 0; r < 4; ++r) {
        float e = __expf((s[m][n][r] - mx[r]) * 0.125f);
        s[m][n][r] = e;
        sum[r] += e;
      }
#pragma unroll
    for (int r = 0; r < 4; ++r) {
      float t = sum[r];
      for (int msk = 1; msk < 16; msk <<= 1) t += __shfl_xor(t, msk, 64);
      sum[r] = 1.f / t;
    }
    for (int n = 0; n < 8; ++n)
      for (int r = 0; r < 4; ++r) s[m][n][r] *= sum[r];
  }
  __syncthreads();

  for (int m = 0; m < 2; ++m)
    for (int n = 0; n < 8; ++n)
      for (int r = 0; r < 4; ++r)
        sP[(w * 32 + m * 16 + lhi * 4 + r) * 128 + n * 16 + l15] = f2bf(s[m][n][r]);
  __syncthreads();

  f32x4 o[2][4];
  for (int m = 0; m < 2; ++m)
    for (int n = 0; n < 4; ++n) o[m][n] = z;
#pragma unroll
  for (int kk = 0; kk < 4; ++kk) {
    bf16x8 ap[2];
#pragma unroll
    for (int m = 0; m < 2; ++m)
      ap[m] = *(const bf16x8*)&sP[(w * 32 + m * 16 + l15) * 128 + kk * 32 + lhi * 8];
#pragma unroll
    for (int n = 0; n < 4; ++n) {
      bf16x8 bv = *(const bf16x8*)&sVt[(n * 16 + l15) * 128 + kk * 32 + lhi * 8];
#pragma unroll
      for (int m = 0; m < 2; ++m)
        o[m][n] = __builtin_amdgcn_mfma_f32_16x16x32_bf16(ap[m], bv, o[m][n], 0, 0, 0);
    }
  }
  for (int m = 0; m < 2; ++m)
    for (int n = 0; n < 4; ++n)
      for (int r = 0; r < 4; ++r) {
        const int q = w * 32 + m * 16 + lhi * 4 + r, c = n * 16 + l15;
        O[base + (size_t)q * 1024 + c] = f2bf(o[m][n][r]);
      }
}

// ---------------------------------------------------------------------------
// LN2D: per-batch-element layernorm over 128x1024. 512 threads.
// ---------------------------------------------------------------------------
__global__ __launch_bounds__(512) void ln2d(
    const float* __restrict__ x, const float* __restrict__ g, const float* __restrict__ bet,
    float* __restrict__ outf, int bstride, uint16_t* __restrict__ outbf) {
  const int b = blockIdx.x, tid = threadIdx.x;
  const float4* xb = (const float4*)(x + (size_t)b * 131072);
  float s = 0.f, ss = 0.f;
  for (int i = tid; i < 32768; i += 512) {
    float4 v = xb[i];
    s += (v.x + v.y) + (v.z + v.w);
    ss += (v.x * v.x + v.y * v.y) + (v.z * v.z + v.w * v.w);
  }
#pragma unroll
  for (int m = 1; m < 64; m <<= 1) {
    s += __shfl_xor(s, m, 64);
    ss += __shfl_xor(ss, m, 64);
  }
  __shared__ float red[16];
  __shared__ float stats[2];
  const int w = tid >> 6;
  if ((tid & 63) == 0) {
    red[w] = s;
    red[8 + w] = ss;
  }
  __syncthreads();
  if (tid == 0) {
    float S = 0.f, SS = 0.f;
    for (int i = 0; i < 8; ++i) { S += red[i]; SS += red[8 + i]; }
    const float mu = S * (1.f / 131072.f);
    const float var = SS * (1.f / 131072.f) - mu * mu;
    stats[0] = mu;
    stats[1] = rsqrtf(var + 1e-5f);
  }
  __syncthreads();
  const float mu = stats[0], rs = stats[1];
  float* of = outf + (size_t)b * (size_t)bstride;
  uint16_t* ob = outbf ? outbf + (size_t)b * 131072 : nullptr;
  const float4* g4 = (const float4*)g;
  const float4* b4 = (const float4*)bet;
  for (int i = tid; i < 32768; i += 512) {
    float4 v = xb[i], gg = g4[i], bb = b4[i];
    float4 o;
    o.x = (v.x - mu) * rs * gg.x + bb.x;
    o.y = (v.y - mu) * rs * gg.y + bb.y;
    o.z = (v.z - mu) * rs * gg.z + bb.z;
    o.w = (v.w - mu) * rs * gg.w + bb.w;
    *(float4*)&of[(size_t)i * 4] = o;
    if (ob) {
      U16x4 u{f2bf(o.x), f2bf(o.y), f2bf(o.z), f2bf(o.w)};
      *(U16x4*)&ob[(size_t)i * 4] = u;
    }
  }
}

// ---------------------------------------------------------------------------
extern "C" void kernel_launch(void* const* d_in, const int* in_sizes, int n_in,
                              void* d_out, int out_size, void* d_ws, size_t ws_size,
                              hipStream_t stream) {
  const float* src = (const float*)d_in[0];
  const float* Wq = (const float*)d_in[1];
  const float* bq = (const float*)d_in[2];
  const float* Wk = (const float*)d_in[3];
  const float* bk = (const float*)d_in[4];
  const float* Wv = (const float*)d_in[5];
  const float* bv = (const float*)d_in[6];
  const float* Wo = (const float*)d_in[7];
  const float* bo = (const float*)d_in[8];
  const float* W1 = (const float*)d_in[9];
  const float* b1 = (const float*)d_in[10];
  const float* W2 = (const float*)d_in[11];
  const float* b2 = (const float*)d_in[12];
  const float* g1 = (const float*)d_in[13];
  const float* be1 = (const float*)d_in[14];
  const float* g2 = (const float*)d_in[15];
  const float* be2 = (const float*)d_in[16];
  float* dout = (float*)d_out;
  char* ws = (char*)d_ws;

  const size_t MB = 1024 * 1024;
  uint16_t* wq_t = (uint16_t*)(ws + 0 * MB);
  uint16_t* wk_t = (uint16_t*)(ws + 2 * MB);
  uint16_t* wv_t = (uint16_t*)(ws + 4 * MB);
  uint16_t* wo_t = (uint16_t*)(ws + 6 * MB);
  uint16_t* w1_t = (uint16_t*)(ws + 8 * MB);   // [4096][1024]
  uint16_t* w2_t = (uint16_t*)(ws + 16 * MB);  // [1024][4096]
  uint16_t* m1bf = (uint16_t*)(ws + 24 * MB);  // final m1 bf16 (phase-B KV src)
  uint16_t* mod2 = (uint16_t*)(ws + 56 * MB);
  uint16_t* QB = (uint16_t*)(ws + 88 * MB);
  uint16_t* KB = (uint16_t*)(ws + 120 * MB);
  uint16_t* VB = (uint16_t*)(ws + 152 * MB);
  uint16_t* ATT = (uint16_t*)(ws + 184 * MB);
  uint16_t* Hbf = QB;  // 128 MB FFN hidden aliases QB..ATT (dead by then)
  uint16_t* mod1 = (uint16_t*)(ws + 216 * MB);
  float* XA = (float*)(ws + 248 * MB);
  float* YF = (float*)(ws + 312 * MB);
  uint16_t* YBF = (uint16_t*)(ws + 376 * MB);
  // total: 408 MB

  dim3 tb(32, 32);
  transpose_cvt<<<dim3(32, 32), tb, 0, stream>>>(Wq, wq_t, 1024, 1024);
  transpose_cvt<<<dim3(32, 32), tb, 0, stream>>>(Wk, wk_t, 1024, 1024);
  transpose_cvt<<<dim3(32, 32), tb, 0, stream>>>(Wv, wv_t, 1024, 1024);
  transpose_cvt<<<dim3(32, 32), tb, 0, stream>>>(Wo, wo_t, 1024, 1024);
  transpose_cvt<<<dim3(128, 32), tb, 0, stream>>>(W1, w1_t, 1024, 4096);
  transpose_cvt<<<dim3(32, 128), tb, 0, stream>>>(W2, w2_t, 4096, 1024);
  cvt_modal<<<16384, 256, 0, stream>>>(src, mod1, mod2);

  auto phase = [&](const uint16_t* qsrc, const uint16_t* kvsrc, int soff,
                   float* out_f, uint16_t* out_bf) {
    // projections: M=16384, N=1024, K=1024 -> 256 blocks, nbn=4
    gemm256<0, false, false><<<256, 512, 0, stream>>>(qsrc, wq_t, bq, nullptr, QB,
                                                      1024, 1024, 4, 0);
    gemm256<0, false, false><<<256, 512, 0, stream>>>(kvsrc, wk_t, bk, nullptr, KB,
                                                      1024, 1024, 4, 0);
    gemm256<0, false, false><<<256, 512, 0, stream>>>(kvsrc, wv_t, bv, nullptr, VB,
                                                      1024, 1024, 4, 0);
    attn_kern<<<2048, 256, 0, stream>>>(QB, KB, VB, ATT);
    // out-proj + residual from src slice
    gemm256<2, false, true><<<256, 512, 0, stream>>>(ATT, wo_t, bo, src, XA,
                                                     1024, 1024, 4, soff);
    ln2d<<<128, 512, 0, stream>>>(XA, g1, be1, YF, 131072, YBF);
    // FFN: 16384x4096x1024 (nbn=16) then 16384x1024x4096 (nbn=4)
    gemm256<0, true, false><<<1024, 512, 0, stream>>>(YBF, w1_t, b1, nullptr, Hbf,
                                                      4096, 1024, 16, 0);
    gemm256<1, false, true><<<256, 512, 0, stream>>>(Hbf, w2_t, b2, YF, XA,
                                                     1024, 4096, 4, 0);
    ln2d<<<128, 512, 0, stream>>>(XA, g2, be2, out_f, 262144, out_bf);
  };

  phase(mod1, mod2, 0, dout, m1bf);
  phase(mod2, m1bf, 128, dout + 131072, nullptr);

  (void)in_sizes; (void)n_in; (void)out_size; (void)ws_size;
}

// Round 4
// 1609.459 us; speedup vs baseline: 1.1769x; 1.0027x over previous
//
#include <hip/hip_runtime.h>
#include <stdint.h>

#define DEV __device__ __forceinline__

typedef __bf16 bf16x8 __attribute__((ext_vector_type(8)));
typedef float  f32x4  __attribute__((ext_vector_type(4)));

struct alignas(8) U16x4 { uint16_t x, y, z, w; };

DEV uint16_t f2bf(float f) {
  union { float f; uint32_t u; } v; v.f = f;
  uint32_t r = v.u + 0x7fffu + ((v.u >> 16) & 1u);
  return (uint16_t)(r >> 16);
}

DEV void gload16(const void* g, void* l) {
  __builtin_amdgcn_global_load_lds((__attribute__((address_space(1))) void*)(g),
                                   (__attribute__((address_space(3))) void*)(l),
                                   16, 0, 0);
}

// ---------------------------------------------------------------------------
// Weight transpose + f32->bf16:  in [R][C] f32  ->  out [C][R] bf16
// ---------------------------------------------------------------------------
__global__ __launch_bounds__(1024) void transpose_cvt(
    const float* __restrict__ in, uint16_t* __restrict__ out, int R, int C) {
  __shared__ float tile[32][33];
  const int tx = threadIdx.x, ty = threadIdx.y;
  const int r = blockIdx.y * 32 + ty, c = blockIdx.x * 32 + tx;
  tile[ty][tx] = in[(size_t)r * C + c];
  __syncthreads();
  const int oc = blockIdx.x * 32 + ty;   // output row (former column)
  const int orr = blockIdx.y * 32 + tx;  // output col (former row)
  out[(size_t)oc * R + orr] = f2bf(tile[tx][ty]);
}

// ---------------------------------------------------------------------------
// Slice src into modal1/modal2 token-major bf16 [16384][1024]
// ---------------------------------------------------------------------------
__global__ __launch_bounds__(256) void cvt_modal(
    const float* __restrict__ src, uint16_t* __restrict__ m1, uint16_t* __restrict__ m2) {
  const int idx = blockIdx.x * 256 + threadIdx.x;  // float4 group
  const int E = idx * 4;
  const int t = E >> 10, dd = E & 1023;
  const size_t s1 = ((size_t)(t >> 7) * 256 + (t & 127)) * 1024 + dd;
  float4 a = *(const float4*)&src[s1];
  float4 b = *(const float4*)&src[s1 + 131072];  // s + 128 rows
  U16x4 pa{f2bf(a.x), f2bf(a.y), f2bf(a.z), f2bf(a.w)};
  U16x4 pb{f2bf(b.x), f2bf(b.y), f2bf(b.z), f2bf(b.w)};
  *(U16x4*)&m1[E] = pa;
  *(U16x4*)&m2[E] = pb;
}

// ---------------------------------------------------------------------------
// GEMM 256x256 tile, BK=32, 8 waves (2Mx4N), 4-buffer 3-deep LDS pipeline.
// ONE barrier / ONE vmcnt per K-tile: ds_reads issued pre-barrier overlap
// other waves' MFMA (wave-skew LDS||MFMA overlap); staging post-barrier.
// Hazards: barrier at tile t guarantees (a) all waves' t+1 staging landed
// (per-wave vmcnt(4) precedes it), (b) all waves' buf[t-1] reads complete
// (their lgkmcnt(0) preceded arrival) before buf[t-1] is re-staged.
// C[M][N] = A[M][K] @ Bt[N][K]^T + bias (+relu) (+resid)
// RESID: 0 none, 1 plain f32 [M][1024], 2 strided src slice (soff)
// Requires M%256==0, N%256==0, K%32==0, K>=128, grid%8==0.
// ---------------------------------------------------------------------------
#define TILE(T, ST, WAITSTR)                                                    \
  {                                                                             \
    const int abase = ((T) & 3) * 8192;                                         \
    const int bbase = 32768 + ((T) & 3) * 8192;                                 \
    const int kn = ((T) + 3) << 5;                                              \
    const int sb = (((T) + 3) & 3) * 8192;                                      \
    bf16x8 afr[4], bfr[4], afr2[4];                                             \
    _Pragma("unroll") for (int n = 0; n < 4; ++n)                               \
        bfr[n] = *(const bf16x8*)&lds[bbase + boff + n * 512];                  \
    _Pragma("unroll") for (int m = 0; m < 4; ++m)                               \
        afr[m] = *(const bf16x8*)&lds[abase + aoff + m * 512];                  \
    asm volatile(WAITSTR ::: "memory");                                         \
    __builtin_amdgcn_s_barrier();                                               \
    if (ST) {                                                                   \
      gload16(gA0 + kn, &lds[sb + wS]);                                         \
      gload16(gA1 + kn, &lds[sb + 4096 + wS]);                                  \
      gload16(gB0 + kn, &lds[32768 + sb + wS]);                                 \
      gload16(gB1 + kn, &lds[32768 + sb + 4096 + wS]);                          \
    }                                                                           \
    asm volatile("s_waitcnt lgkmcnt(0)" ::: "memory");                          \
    __builtin_amdgcn_sched_barrier(0);                                          \
    __builtin_amdgcn_s_setprio(1);                                              \
    _Pragma("unroll") for (int m = 0; m < 4; ++m)                               \
        _Pragma("unroll") for (int n = 0; n < 4; ++n)                           \
        acc[m][n] = __builtin_amdgcn_mfma_f32_16x16x32_bf16(afr[m], bfr[n],     \
                                                            acc[m][n], 0, 0, 0);\
    __builtin_amdgcn_s_setprio(0);                                              \
    _Pragma("unroll") for (int m = 0; m < 4; ++m)                               \
        afr2[m] = *(const bf16x8*)&lds[abase + aoff + (m + 4) * 512];           \
    asm volatile("s_waitcnt lgkmcnt(0)" ::: "memory");                          \
    __builtin_amdgcn_sched_barrier(0);                                          \
    __builtin_amdgcn_s_setprio(1);                                              \
    _Pragma("unroll") for (int m = 0; m < 4; ++m)                               \
        _Pragma("unroll") for (int n = 0; n < 4; ++n)                           \
        acc[m + 4][n] = __builtin_amdgcn_mfma_f32_16x16x32_bf16(                \
            afr2[m], bfr[n], acc[m + 4][n], 0, 0, 0);                           \
    __builtin_amdgcn_s_setprio(0);                                              \
    __builtin_amdgcn_sched_barrier(0);                                          \
  }

template <int RESID, bool RELU, bool OUTF32>
__global__ __launch_bounds__(512, 2) void gemm256(
    const uint16_t* __restrict__ A, const uint16_t* __restrict__ Bt,
    const float* __restrict__ bias, const float* __restrict__ resid,
    void* __restrict__ outp, int N, int K, int nbn, int soff) {
  __shared__ __align__(16) uint16_t lds[65536];  // 128 KiB: A 4x8192, B 4x8192 elems

  // ---- block swizzle: XCD-contiguous s, bm-major decode ----
  const int nwg = gridDim.x;
  const int s = (blockIdx.x & 7) * (nwg >> 3) + (blockIdx.x >> 3);
  const int bm = s / nbn, bn = s % nbn;
  const int brow = bm << 8, bcol = bn << 8;

  const int tid = threadIdx.x;
  const int w = tid >> 6, lane = tid & 63, l15 = lane & 15, lhi = lane >> 4;
  const int wm = w >> 2, wn = w & 3;

  // ---- staging addressing (linear LDS dest, inverse-swizzled global src) ----
  const int srow = w * 16 + (lane >> 2);              // 0..127 within half
  const int cswz = (lane & 3) ^ ((lane >> 3) & 3);    // global chunk fetched
  const uint16_t* gA0 = A + (size_t)(brow + srow) * K + cswz * 8;
  const uint16_t* gA1 = A + (size_t)(brow + 128 + srow) * K + cswz * 8;
  const uint16_t* gB0 = Bt + (size_t)(bcol + srow) * K + cswz * 8;
  const uint16_t* gB1 = Bt + (size_t)(bcol + 128 + srow) * K + cswz * 8;
  const int wS = w * 512;  // wave's element offset within a 4096-elem half

  // ---- read addressing (swizzled chunk position) ----
  const int p = lhi ^ ((l15 >> 1) & 3);
  const int aoff = (wm * 128 + l15) * 32 + p * 8;
  const int boff = (wn * 64 + l15) * 32 + p * 8;

  f32x4 acc[8][4];
  const f32x4 z = {0.f, 0.f, 0.f, 0.f};
#pragma unroll
  for (int m = 0; m < 8; ++m)
#pragma unroll
    for (int n = 0; n < 4; ++n) acc[m][n] = z;

  const int nt = K >> 5;

  // ---- prologue: stage tiles 0,1,2 ----
#pragma unroll
  for (int pt = 0; pt < 3; ++pt) {
    const int sb = pt * 8192, kk = pt << 5;
    gload16(gA0 + kk, &lds[sb + wS]);
    gload16(gA1 + kk, &lds[sb + 4096 + wS]);
    gload16(gB0 + kk, &lds[32768 + sb + wS]);
    gload16(gB1 + kk, &lds[32768 + sb + 4096 + wS]);
  }
  asm volatile("s_waitcnt vmcnt(8)" ::: "memory");  // tile 0 landed
  __builtin_amdgcn_s_barrier();
  __builtin_amdgcn_sched_barrier(0);

  int t = 0;
  for (; t < nt - 3; ++t) TILE(t, true, "s_waitcnt vmcnt(4)");
  TILE(t, false, "s_waitcnt vmcnt(4)");
  ++t;
  TILE(t, false, "s_waitcnt vmcnt(0)");
  ++t;
  TILE(t, false, "");

  // ---- epilogue ----
#pragma unroll
  for (int n = 0; n < 4; ++n) {
    const int col = bcol + wn * 64 + n * 16 + l15;
    const float bs = bias[col];
#pragma unroll
    for (int m = 0; m < 8; ++m) {
#pragma unroll
      for (int r = 0; r < 4; ++r) {
        const int row = brow + wm * 128 + m * 16 + lhi * 4 + r;
        float v = acc[m][n][r] + bs;
        if (RELU) v = fmaxf(v, 0.f);
        if (RESID == 1) v += resid[(size_t)row * 1024 + col];
        if (RESID == 2)
          v += resid[((size_t)(row >> 7) * 256 + soff + (row & 127)) * 1024 + col];
        if (OUTF32)
          ((float*)outp)[(size_t)row * N + col] = v;
        else
          ((uint16_t*)outp)[(size_t)row * N + col] = f2bf(v);
      }
    }
  }
}

// ---------------------------------------------------------------------------
// Attention core: one block per (b,h). S=128, dh=64. Q,K,V bf16 [t][1024].
// ---------------------------------------------------------------------------
__global__ __launch_bounds__(256) void attn_kern(
    const uint16_t* __restrict__ Q, const uint16_t* __restrict__ Kv,
    const uint16_t* __restrict__ V, uint16_t* __restrict__ O) {
  __shared__ uint16_t sm[24576];  // 48 KB: [Q 16K | K 16K | Vt 16K]; P aliases Q+K
  uint16_t* sQ = sm;
  uint16_t* sK = sm + 8192;
  uint16_t* sVt = sm + 16384;
  uint16_t* sP = sm;  // 128x128 bf16 = 32KB, reuses Q+K after barrier
  const int bh = blockIdx.x, b = bh >> 4, h = bh & 15;
  const int tid = threadIdx.x, w = tid >> 6, lane = tid & 63, l15 = lane & 15, lhi = lane >> 4;
  const size_t base = (size_t)b * 131072 + h * 64;

  for (int i = 0; i < 4; ++i) {
    const int gidx = i * 256 + tid;
    const int row = gidx >> 3, co = (gidx & 7) * 8;
    *(uint4*)&sQ[row * 64 + co] = *(const uint4*)&Q[base + (size_t)row * 1024 + co];
    *(uint4*)&sK[row * 64 + co] = *(const uint4*)&Kv[base + (size_t)row * 1024 + co];
  }
  {
    const int r = tid >> 1, cb = (tid & 1) * 32;
    for (int jj = 0; jj < 4; ++jj) {
      uint4 vv = *(const uint4*)&V[base + (size_t)r * 1024 + cb + jj * 8];
      const uint16_t* e = (const uint16_t*)&vv;
      for (int j = 0; j < 8; ++j) sVt[(cb + jj * 8 + j) * 128 + r] = e[j];
    }
  }
  __syncthreads();

  f32x4 s[2][8];
  const f32x4 z = {0.f, 0.f, 0.f, 0.f};
  for (int m = 0; m < 2; ++m)
    for (int n = 0; n < 8; ++n) s[m][n] = z;
#pragma unroll
  for (int kk = 0; kk < 2; ++kk) {
    bf16x8 aq[2];
#pragma unroll
    for (int m = 0; m < 2; ++m)
      aq[m] = *(const bf16x8*)&sQ[(w * 32 + m * 16 + l15) * 64 + kk * 32 + lhi * 8];
#pragma unroll
    for (int n = 0; n < 8; ++n) {
      bf16x8 bk = *(const bf16x8*)&sK[(n * 16 + l15) * 64 + kk * 32 + lhi * 8];
#pragma unroll
      for (int m = 0; m < 2; ++m)
        s[m][n] = __builtin_amdgcn_mfma_f32_16x16x32_bf16(aq[m], bk, s[m][n], 0, 0, 0);
    }
  }

  for (int m = 0; m < 2; ++m) {
    float mx[4], sum[4];
#pragma unroll
    for (int r = 0; r < 4; ++r) {
      float v = s[m][0][r];
      for (int n = 1; n < 8; ++n) v = fmaxf(v, s[m][n][r]);
      for (int msk = 1; msk < 16; msk <<= 1) v = fmaxf(v, __shfl_xor(v, msk, 64));
      mx[r] = v;
      sum[r] = 0.f;
    }
    for (int n = 0; n < 8; ++n)
      for (int r = 0; r < 4; ++r) {
        float e = __expf((s[m][n][r] - mx[r]) * 0.125f);
        s[m][n][r] = e;
        sum[r] += e;
      }
#pragma unroll
    for (int r = 0; r < 4; ++r) {
      float t = sum[r];
      for (int msk = 1; msk < 16; msk <<= 1) t += __shfl_xor(t, msk, 64);
      sum[r] = 1.f / t;
    }
    for (int n = 0; n < 8; ++n)
      for (int r = 0; r < 4; ++r) s[m][n][r] *= sum[r];
  }
  __syncthreads();

  for (int m = 0; m < 2; ++m)
    for (int n = 0; n < 8; ++n)
      for (int r = 0; r < 4; ++r)
        sP[(w * 32 + m * 16 + lhi * 4 + r) * 128 + n * 16 + l15] = f2bf(s[m][n][r]);
  __syncthreads();

  f32x4 o[2][4];
  for (int m = 0; m < 2; ++m)
    for (int n = 0; n < 4; ++n) o[m][n] = z;
#pragma unroll
  for (int kk = 0; kk < 4; ++kk) {
    bf16x8 ap[2];
#pragma unroll
    for (int m = 0; m < 2; ++m)
      ap[m] = *(const bf16x8*)&sP[(w * 32 + m * 16 + l15) * 128 + kk * 32 + lhi * 8];
#pragma unroll
    for (int n = 0; n < 4; ++n) {
      bf16x8 bv = *(const bf16x8*)&sVt[(n * 16 + l15) * 128 + kk * 32 + lhi * 8];
#pragma unroll
      for (int m = 0; m < 2; ++m)
        o[m][n] = __builtin_amdgcn_mfma_f32_16x16x32_bf16(ap[m], bv, o[m][n], 0, 0, 0);
    }
  }
  for (int m = 0; m < 2; ++m)
    for (int n = 0; n < 4; ++n)
      for (int r = 0; r < 4; ++r) {
        const int q = w * 32 + m * 16 + lhi * 4 + r, c = n * 16 + l15;
        O[base + (size_t)q * 1024 + c] = f2bf(o[m][n][r]);
      }
}

// ---------------------------------------------------------------------------
// LN2D: per-batch-element layernorm over 128x1024. 512 threads.
// ---------------------------------------------------------------------------
__global__ __launch_bounds__(512) void ln2d(
    const float* __restrict__ x, const float* __restrict__ g, const float* __restrict__ bet,
    float* __restrict__ outf, int bstride, uint16_t* __restrict__ outbf) {
  const int b = blockIdx.x, tid = threadIdx.x;
  const float4* xb = (const float4*)(x + (size_t)b * 131072);
  float s = 0.f, ss = 0.f;
  for (int i = tid; i < 32768; i += 512) {
    float4 v = xb[i];
    s += (v.x + v.y) + (v.z + v.w);
    ss += (v.x * v.x + v.y * v.y) + (v.z * v.z + v.w * v.w);
  }
#pragma unroll
  for (int m = 1; m < 64; m <<= 1) {
    s += __shfl_xor(s, m, 64);
    ss += __shfl_xor(ss, m, 64);
  }
  __shared__ float red[16];
  __shared__ float stats[2];
  const int w = tid >> 6;
  if ((tid & 63) == 0) {
    red[w] = s;
    red[8 + w] = ss;
  }
  __syncthreads();
  if (tid == 0) {
    float S = 0.f, SS = 0.f;
    for (int i = 0; i < 8; ++i) { S += red[i]; SS += red[8 + i]; }
    const float mu = S * (1.f / 131072.f);
    const float var = SS * (1.f / 131072.f) - mu * mu;
    stats[0] = mu;
    stats[1] = rsqrtf(var + 1e-5f);
  }
  __syncthreads();
  const float mu = stats[0], rs = stats[1];
  float* of = outf + (size_t)b * (size_t)bstride;
  uint16_t* ob = outbf ? outbf + (size_t)b * 131072 : nullptr;
  const float4* g4 = (const float4*)g;
  const float4* b4 = (const float4*)bet;
  for (int i = tid; i < 32768; i += 512) {
    float4 v = xb[i], gg = g4[i], bb = b4[i];
    float4 o;
    o.x = (v.x - mu) * rs * gg.x + bb.x;
    o.y = (v.y - mu) * rs * gg.y + bb.y;
    o.z = (v.z - mu) * rs * gg.z + bb.z;
    o.w = (v.w - mu) * rs * gg.w + bb.w;
    *(float4*)&of[(size_t)i * 4] = o;
    if (ob) {
      U16x4 u{f2bf(o.x), f2bf(o.y), f2bf(o.z), f2bf(o.w)};
      *(U16x4*)&ob[(size_t)i * 4] = u;
    }
  }
}

// ---------------------------------------------------------------------------
extern "C" void kernel_launch(void* const* d_in, const int* in_sizes, int n_in,
                              void* d_out, int out_size, void* d_ws, size_t ws_size,
                              hipStream_t stream) {
  const float* src = (const float*)d_in[0];
  const float* Wq = (const float*)d_in[1];
  const float* bq = (const float*)d_in[2];
  const float* Wk = (const float*)d_in[3];
  const float* bk = (const float*)d_in[4];
  const float* Wv = (const float*)d_in[5];
  const float* bv = (const float*)d_in[6];
  const float* Wo = (const float*)d_in[7];
  const float* bo = (const float*)d_in[8];
  const float* W1 = (const float*)d_in[9];
  const float* b1 = (const float*)d_in[10];
  const float* W2 = (const float*)d_in[11];
  const float* b2 = (const float*)d_in[12];
  const float* g1 = (const float*)d_in[13];
  const float* be1 = (const float*)d_in[14];
  const float* g2 = (const float*)d_in[15];
  const float* be2 = (const float*)d_in[16];
  float* dout = (float*)d_out;
  char* ws = (char*)d_ws;

  const size_t MB = 1024 * 1024;
  uint16_t* wq_t = (uint16_t*)(ws + 0 * MB);
  uint16_t* wk_t = (uint16_t*)(ws + 2 * MB);
  uint16_t* wv_t = (uint16_t*)(ws + 4 * MB);
  uint16_t* wo_t = (uint16_t*)(ws + 6 * MB);
  uint16_t* w1_t = (uint16_t*)(ws + 8 * MB);   // [4096][1024]
  uint16_t* w2_t = (uint16_t*)(ws + 16 * MB);  // [1024][4096]
  uint16_t* m1bf = (uint16_t*)(ws + 24 * MB);  // final m1 bf16 (phase-B KV src)
  uint16_t* mod2 = (uint16_t*)(ws + 56 * MB);
  uint16_t* QB = (uint16_t*)(ws + 88 * MB);
  uint16_t* KB = (uint16_t*)(ws + 120 * MB);
  uint16_t* VB = (uint16_t*)(ws + 152 * MB);
  uint16_t* ATT = (uint16_t*)(ws + 184 * MB);
  uint16_t* Hbf = QB;  // 128 MB FFN hidden aliases QB..ATT (dead by then)
  uint16_t* mod1 = (uint16_t*)(ws + 216 * MB);
  float* XA = (float*)(ws + 248 * MB);
  float* YF = (float*)(ws + 312 * MB);
  uint16_t* YBF = (uint16_t*)(ws + 376 * MB);
  // total: 408 MB

  dim3 tb(32, 32);
  transpose_cvt<<<dim3(32, 32), tb, 0, stream>>>(Wq, wq_t, 1024, 1024);
  transpose_cvt<<<dim3(32, 32), tb, 0, stream>>>(Wk, wk_t, 1024, 1024);
  transpose_cvt<<<dim3(32, 32), tb, 0, stream>>>(Wv, wv_t, 1024, 1024);
  transpose_cvt<<<dim3(32, 32), tb, 0, stream>>>(Wo, wo_t, 1024, 1024);
  transpose_cvt<<<dim3(128, 32), tb, 0, stream>>>(W1, w1_t, 1024, 4096);
  transpose_cvt<<<dim3(32, 128), tb, 0, stream>>>(W2, w2_t, 4096, 1024);
  cvt_modal<<<16384, 256, 0, stream>>>(src, mod1, mod2);

  auto phase = [&](const uint16_t* qsrc, const uint16_t* kvsrc, int soff,
                   float* out_f, uint16_t* out_bf) {
    // projections: M=16384, N=1024, K=1024 -> 256 blocks, nbn=4
    gemm256<0, false, false><<<256, 512, 0, stream>>>(qsrc, wq_t, bq, nullptr, QB,
                                                      1024, 1024, 4, 0);
    gemm256<0, false, false><<<256, 512, 0, stream>>>(kvsrc, wk_t, bk, nullptr, KB,
                                                      1024, 1024, 4, 0);
    gemm256<0, false, false><<<256, 512, 0, stream>>>(kvsrc, wv_t, bv, nullptr, VB,
                                                      1024, 1024, 4, 0);
    attn_kern<<<2048, 256, 0, stream>>>(QB, KB, VB, ATT);
    // out-proj + residual from src slice
    gemm256<2, false, true><<<256, 512, 0, stream>>>(ATT, wo_t, bo, src, XA,
                                                     1024, 1024, 4, soff);
    ln2d<<<128, 512, 0, stream>>>(XA, g1, be1, YF, 131072, YBF);
    // FFN: 16384x4096x1024 (nbn=16) then 16384x1024x4096 (nbn=4)
    gemm256<0, true, false><<<1024, 512, 0, stream>>>(YBF, w1_t, b1, nullptr, Hbf,
                                                      4096, 1024, 16, 0);
    gemm256<1, false, true><<<256, 512, 0, stream>>>(Hbf, w2_t, b2, YF, XA,
                                                     1024, 4096, 4, 0);
    ln2d<<<128, 512, 0, stream>>>(XA, g2, be2, out_f, 262144, out_bf);
  };

  phase(mod1, mod2, 0, dout, m1bf);
  phase(mod2, m1bf, 128, dout + 131072, nullptr);

  (void)in_sizes; (void)n_in; (void)out_size; (void)ws_size;
}

// Round 5
// 1473.479 us; speedup vs baseline: 1.2856x; 1.0923x over previous
//
#include <hip/hip_runtime.h>
#include <stdint.h>

#define DEV __device__ __forceinline__

typedef __bf16 bf16x8 __attribute__((ext_vector_type(8)));
typedef float  f32x4  __attribute__((ext_vector_type(4)));

struct alignas(8) U16x4 { uint16_t x, y, z, w; };

DEV uint16_t f2bf(float f) {
  union { float f; uint32_t u; } v; v.f = f;
  uint32_t r = v.u + 0x7fffu + ((v.u >> 16) & 1u);
  return (uint16_t)(r >> 16);
}

DEV void gload16(const void* g, void* l) {
  __builtin_amdgcn_global_load_lds((__attribute__((address_space(1))) void*)(g),
                                   (__attribute__((address_space(3))) void*)(l),
                                   16, 0, 0);
}

// ---------------------------------------------------------------------------
// Weight transpose + f32->bf16:  in [R][C] f32  ->  out [C][R] bf16
// ---------------------------------------------------------------------------
__global__ __launch_bounds__(1024) void transpose_cvt(
    const float* __restrict__ in, uint16_t* __restrict__ out, int R, int C) {
  __shared__ float tile[32][33];
  const int tx = threadIdx.x, ty = threadIdx.y;
  const int r = blockIdx.y * 32 + ty, c = blockIdx.x * 32 + tx;
  tile[ty][tx] = in[(size_t)r * C + c];
  __syncthreads();
  const int oc = blockIdx.x * 32 + ty;   // output row (former column)
  const int orr = blockIdx.y * 32 + tx;  // output col (former row)
  out[(size_t)oc * R + orr] = f2bf(tile[tx][ty]);
}

// ---------------------------------------------------------------------------
// Slice src into modal1/modal2 token-major bf16 [16384][1024]
// ---------------------------------------------------------------------------
__global__ __launch_bounds__(256) void cvt_modal(
    const float* __restrict__ src, uint16_t* __restrict__ m1, uint16_t* __restrict__ m2) {
  const int idx = blockIdx.x * 256 + threadIdx.x;  // float4 group
  const int E = idx * 4;
  const int t = E >> 10, dd = E & 1023;
  const size_t s1 = ((size_t)(t >> 7) * 256 + (t & 127)) * 1024 + dd;
  float4 a = *(const float4*)&src[s1];
  float4 b = *(const float4*)&src[s1 + 131072];  // s + 128 rows
  U16x4 pa{f2bf(a.x), f2bf(a.y), f2bf(a.z), f2bf(a.w)};
  U16x4 pb{f2bf(b.x), f2bf(b.y), f2bf(b.z), f2bf(b.w)};
  *(U16x4*)&m1[E] = pa;
  *(U16x4*)&m2[E] = pb;
}

// ---------------------------------------------------------------------------
// GEMM 256x256 tile, BK=32, 16 waves (4Mx4N, 64x64 per wave), 4-buffer
// 3-deep LDS pipeline, counted vmcnt, chunk-XOR swizzle, XCD-contiguous +
// bm-major block order. 4 waves/SIMD (acc=64 + frags=32 VGPR) for TLP.
// Per tile: single {8 ds_read -> barrier -> 2 gload_lds -> lgkm(0) -> 16 MFMA}.
// C[M][N] = A[M][K] @ Bt[N][K]^T + bias (+relu) (+resid)
// RESID: 0 none, 1 plain f32 [M][1024], 2 strided src slice (soff)
// Requires M%256==0, N%256==0, K%32==0, K>=128, grid%8==0.
// ---------------------------------------------------------------------------
#define TILE(T, ST, WAITSTR)                                                    \
  {                                                                             \
    const int abase = ((T) & 3) * 8192;                                         \
    const int bbase = 32768 + ((T) & 3) * 8192;                                 \
    const int kn = ((T) + 3) << 5;                                              \
    const int sb = (((T) + 3) & 3) * 8192;                                      \
    bf16x8 afr[4], bfr[4];                                                      \
    _Pragma("unroll") for (int n = 0; n < 4; ++n)                               \
        bfr[n] = *(const bf16x8*)&lds[bbase + boff + n * 512];                  \
    _Pragma("unroll") for (int m = 0; m < 4; ++m)                               \
        afr[m] = *(const bf16x8*)&lds[abase + aoff + m * 512];                  \
    asm volatile(WAITSTR ::: "memory");                                         \
    __builtin_amdgcn_s_barrier();                                               \
    if (ST) {                                                                   \
      gload16(gA + kn, ldsA);                                                   \
      gload16(gB + kn, ldsB);                                                   \
      /* ldsA/ldsB are buf-0 bases; add sb via pointer math below */            \
    }                                                                           \
    asm volatile("s_waitcnt lgkmcnt(0)" ::: "memory");                          \
    __builtin_amdgcn_sched_barrier(0);                                          \
    __builtin_amdgcn_s_setprio(1);                                              \
    _Pragma("unroll") for (int m = 0; m < 4; ++m)                               \
        _Pragma("unroll") for (int n = 0; n < 4; ++n)                           \
        acc[m][n] = __builtin_amdgcn_mfma_f32_16x16x32_bf16(afr[m], bfr[n],     \
                                                            acc[m][n], 0, 0, 0);\
    __builtin_amdgcn_s_setprio(0);                                              \
    __builtin_amdgcn_sched_barrier(0);                                          \
  }

// variant with explicit staging buffer offset
#define TILE2(T, ST, WAITSTR)                                                   \
  {                                                                             \
    const int abase = ((T) & 3) * 8192;                                         \
    const int bbase = 32768 + ((T) & 3) * 8192;                                 \
    bf16x8 afr[4], bfr[4];                                                      \
    _Pragma("unroll") for (int n = 0; n < 4; ++n)                               \
        bfr[n] = *(const bf16x8*)&lds[bbase + boff + n * 512];                  \
    _Pragma("unroll") for (int m = 0; m < 4; ++m)                               \
        afr[m] = *(const bf16x8*)&lds[abase + aoff + m * 512];                  \
    asm volatile(WAITSTR ::: "memory");                                         \
    __builtin_amdgcn_s_barrier();                                               \
    if (ST) {                                                                   \
      const int kn = ((T) + 3) << 5;                                            \
      const int sb = (((T) + 3) & 3) * 8192;                                    \
      gload16(gA + kn, &lds[sb + wS]);                                          \
      gload16(gB + kn, &lds[32768 + sb + wS]);                                  \
    }                                                                           \
    asm volatile("s_waitcnt lgkmcnt(0)" ::: "memory");                          \
    __builtin_amdgcn_sched_barrier(0);                                          \
    __builtin_amdgcn_s_setprio(1);                                              \
    _Pragma("unroll") for (int m = 0; m < 4; ++m)                               \
        _Pragma("unroll") for (int n = 0; n < 4; ++n)                           \
        acc[m][n] = __builtin_amdgcn_mfma_f32_16x16x32_bf16(afr[m], bfr[n],     \
                                                            acc[m][n], 0, 0, 0);\
    __builtin_amdgcn_s_setprio(0);                                              \
    __builtin_amdgcn_sched_barrier(0);                                          \
  }

template <int RESID, bool RELU, bool OUTF32>
__global__ __launch_bounds__(1024, 1) void gemm256(
    const uint16_t* __restrict__ A, const uint16_t* __restrict__ Bt,
    const float* __restrict__ bias, const float* __restrict__ resid,
    void* __restrict__ outp, int N, int K, int nbn, int soff) {
  __shared__ __align__(16) uint16_t lds[65536];  // 128 KiB: A 4x8192, B 4x8192 elems

  // ---- block swizzle: XCD-contiguous s, bm-major decode ----
  const int nwg = gridDim.x;
  const int s = (blockIdx.x & 7) * (nwg >> 3) + (blockIdx.x >> 3);
  const int bm = s / nbn, bn = s % nbn;
  const int brow = bm << 8, bcol = bn << 8;

  const int tid = threadIdx.x;
  const int w = tid >> 6, lane = tid & 63, l15 = lane & 15, lhi = lane >> 4;
  const int wm = w >> 2, wn = w & 3;

  // ---- staging addressing (linear LDS dest, inverse-swizzled global src) ----
  // thread stages row tid>>2 (0..255), chunk tid&3; inverse swizzle on source
  const int srow = tid >> 2;
  const int cswz = (tid & 3) ^ ((tid >> 3) & 3);
  const uint16_t* gA = A + (size_t)(brow + srow) * K + cswz * 8;
  const uint16_t* gB = Bt + (size_t)(bcol + srow) * K + cswz * 8;
  const int wS = w * 512;  // wave-uniform LDS base (elems); HW adds lane*16B

  // ---- read addressing (swizzled chunk position) ----
  const int p = lhi ^ ((l15 >> 1) & 3);
  const int aoff = (wm * 64 + l15) * 32 + p * 8;
  const int boff = (wn * 64 + l15) * 32 + p * 8;

  f32x4 acc[4][4];
  const f32x4 z = {0.f, 0.f, 0.f, 0.f};
#pragma unroll
  for (int m = 0; m < 4; ++m)
#pragma unroll
    for (int n = 0; n < 4; ++n) acc[m][n] = z;

  const int nt = K >> 5;

  // ---- prologue: stage tiles 0,1,2 (2 loads each) ----
#pragma unroll
  for (int pt = 0; pt < 3; ++pt) {
    const int sb = pt * 8192, kk = pt << 5;
    gload16(gA + kk, &lds[sb + wS]);
    gload16(gB + kk, &lds[32768 + sb + wS]);
  }
  asm volatile("s_waitcnt vmcnt(4)" ::: "memory");  // tile 0 landed
  __builtin_amdgcn_s_barrier();
  __builtin_amdgcn_sched_barrier(0);

  int t = 0;
  for (; t < nt - 3; ++t) TILE2(t, true, "s_waitcnt vmcnt(2)");
  TILE2(t, false, "s_waitcnt vmcnt(2)");
  ++t;
  TILE2(t, false, "s_waitcnt vmcnt(0)");
  ++t;
  TILE2(t, false, "");

  // ---- epilogue: wave writes 64x64 at (brow+wm*64, bcol+wn*64) ----
#pragma unroll
  for (int n = 0; n < 4; ++n) {
    const int col = bcol + wn * 64 + n * 16 + l15;
    const float bs = bias[col];
#pragma unroll
    for (int m = 0; m < 4; ++m) {
#pragma unroll
      for (int r = 0; r < 4; ++r) {
        const int row = brow + wm * 64 + m * 16 + lhi * 4 + r;
        float v = acc[m][n][r] + bs;
        if (RELU) v = fmaxf(v, 0.f);
        if (RESID == 1) v += resid[(size_t)row * 1024 + col];
        if (RESID == 2)
          v += resid[((size_t)(row >> 7) * 256 + soff + (row & 127)) * 1024 + col];
        if (OUTF32)
          ((float*)outp)[(size_t)row * N + col] = v;
        else
          ((uint16_t*)outp)[(size_t)row * N + col] = f2bf(v);
      }
    }
  }
}

// ---------------------------------------------------------------------------
// Attention core: one block per (b,h). S=128, dh=64. Q,K,V bf16 [t][1024].
// ---------------------------------------------------------------------------
__global__ __launch_bounds__(256) void attn_kern(
    const uint16_t* __restrict__ Q, const uint16_t* __restrict__ Kv,
    const uint16_t* __restrict__ V, uint16_t* __restrict__ O) {
  __shared__ uint16_t sm[24576];  // 48 KB: [Q 16K | K 16K | Vt 16K]; P aliases Q+K
  uint16_t* sQ = sm;
  uint16_t* sK = sm + 8192;
  uint16_t* sVt = sm + 16384;
  uint16_t* sP = sm;  // 128x128 bf16 = 32KB, reuses Q+K after barrier
  const int bh = blockIdx.x, b = bh >> 4, h = bh & 15;
  const int tid = threadIdx.x, w = tid >> 6, lane = tid & 63, l15 = lane & 15, lhi = lane >> 4;
  const size_t base = (size_t)b * 131072 + h * 64;

  for (int i = 0; i < 4; ++i) {
    const int gidx = i * 256 + tid;
    const int row = gidx >> 3, co = (gidx & 7) * 8;
    *(uint4*)&sQ[row * 64 + co] = *(const uint4*)&Q[base + (size_t)row * 1024 + co];
    *(uint4*)&sK[row * 64 + co] = *(const uint4*)&Kv[base + (size_t)row * 1024 + co];
  }
  {
    const int r = tid >> 1, cb = (tid & 1) * 32;
    for (int jj = 0; jj < 4; ++jj) {
      uint4 vv = *(const uint4*)&V[base + (size_t)r * 1024 + cb + jj * 8];
      const uint16_t* e = (const uint16_t*)&vv;
      for (int j = 0; j < 8; ++j) sVt[(cb + jj * 8 + j) * 128 + r] = e[j];
    }
  }
  __syncthreads();

  f32x4 s[2][8];
  const f32x4 z = {0.f, 0.f, 0.f, 0.f};
  for (int m = 0; m < 2; ++m)
    for (int n = 0; n < 8; ++n) s[m][n] = z;
#pragma unroll
  for (int kk = 0; kk < 2; ++kk) {
    bf16x8 aq[2];
#pragma unroll
    for (int m = 0; m < 2; ++m)
      aq[m] = *(const bf16x8*)&sQ[(w * 32 + m * 16 + l15) * 64 + kk * 32 + lhi * 8];
#pragma unroll
    for (int n = 0; n < 8; ++n) {
      bf16x8 bk = *(const bf16x8*)&sK[(n * 16 + l15) * 64 + kk * 32 + lhi * 8];
#pragma unroll
      for (int m = 0; m < 2; ++m)
        s[m][n] = __builtin_amdgcn_mfma_f32_16x16x32_bf16(aq[m], bk, s[m][n], 0, 0, 0);
    }
  }

  for (int m = 0; m < 2; ++m) {
    float mx[4], sum[4];
#pragma unroll
    for (int r = 0; r < 4; ++r) {
      float v = s[m][0][r];
      for (int n = 1; n < 8; ++n) v = fmaxf(v, s[m][n][r]);
      for (int msk = 1; msk < 16; msk <<= 1) v = fmaxf(v, __shfl_xor(v, msk, 64));
      mx[r] = v;
      sum[r] = 0.f;
    }
    for (int n = 0; n < 8; ++n)
      for (int r = 0; r < 4; ++r) {
        float e = __expf((s[m][n][r] - mx[r]) * 0.125f);
        s[m][n][r] = e;
        sum[r] += e;
      }
#pragma unroll
    for (int r = 0; r < 4; ++r) {
      float t = sum[r];
      for (int msk = 1; msk < 16; msk <<= 1) t += __shfl_xor(t, msk, 64);
      sum[r] = 1.f / t;
    }
    for (int n = 0; n < 8; ++n)
      for (int r = 0; r < 4; ++r) s[m][n][r] *= sum[r];
  }
  __syncthreads();

  for (int m = 0; m < 2; ++m)
    for (int n = 0; n < 8; ++n)
      for (int r = 0; r < 4; ++r)
        sP[(w * 32 + m * 16 + lhi * 4 + r) * 128 + n * 16 + l15] = f2bf(s[m][n][r]);
  __syncthreads();

  f32x4 o[2][4];
  for (int m = 0; m < 2; ++m)
    for (int n = 0; n < 4; ++n) o[m][n] = z;
#pragma unroll
  for (int kk = 0; kk < 4; ++kk) {
    bf16x8 ap[2];
#pragma unroll
    for (int m = 0; m < 2; ++m)
      ap[m] = *(const bf16x8*)&sP[(w * 32 + m * 16 + l15) * 128 + kk * 32 + lhi * 8];
#pragma unroll
    for (int n = 0; n < 4; ++n) {
      bf16x8 bv = *(const bf16x8*)&sVt[(n * 16 + l15) * 128 + kk * 32 + lhi * 8];
#pragma unroll
      for (int m = 0; m < 2; ++m)
        o[m][n] = __builtin_amdgcn_mfma_f32_16x16x32_bf16(ap[m], bv, o[m][n], 0, 0, 0);
    }
  }
  for (int m = 0; m < 2; ++m)
    for (int n = 0; n < 4; ++n)
      for (int r = 0; r < 4; ++r) {
        const int q = w * 32 + m * 16 + lhi * 4 + r, c = n * 16 + l15;
        O[base + (size_t)q * 1024 + c] = f2bf(o[m][n][r]);
      }
}

// ---------------------------------------------------------------------------
// LN2D: per-batch-element layernorm over 128x1024. 512 threads.
// ---------------------------------------------------------------------------
__global__ __launch_bounds__(512) void ln2d(
    const float* __restrict__ x, const float* __restrict__ g, const float* __restrict__ bet,
    float* __restrict__ outf, int bstride, uint16_t* __restrict__ outbf) {
  const int b = blockIdx.x, tid = threadIdx.x;
  const float4* xb = (const float4*)(x + (size_t)b * 131072);
  float s = 0.f, ss = 0.f;
  for (int i = tid; i < 32768; i += 512) {
    float4 v = xb[i];
    s += (v.x + v.y) + (v.z + v.w);
    ss += (v.x * v.x + v.y * v.y) + (v.z * v.z + v.w * v.w);
  }
#pragma unroll
  for (int m = 1; m < 64; m <<= 1) {
    s += __shfl_xor(s, m, 64);
    ss += __shfl_xor(ss, m, 64);
  }
  __shared__ float red[16];
  __shared__ float stats[2];
  const int w = tid >> 6;
  if ((tid & 63) == 0) {
    red[w] = s;
    red[8 + w] = ss;
  }
  __syncthreads();
  if (tid == 0) {
    float S = 0.f, SS = 0.f;
    for (int i = 0; i < 8; ++i) { S += red[i]; SS += red[8 + i]; }
    const float mu = S * (1.f / 131072.f);
    const float var = SS * (1.f / 131072.f) - mu * mu;
    stats[0] = mu;
    stats[1] = rsqrtf(var + 1e-5f);
  }
  __syncthreads();
  const float mu = stats[0], rs = stats[1];
  float* of = outf + (size_t)b * (size_t)bstride;
  uint16_t* ob = outbf ? outbf + (size_t)b * 131072 : nullptr;
  const float4* g4 = (const float4*)g;
  const float4* b4 = (const float4*)bet;
  for (int i = tid; i < 32768; i += 512) {
    float4 v = xb[i], gg = g4[i], bb = b4[i];
    float4 o;
    o.x = (v.x - mu) * rs * gg.x + bb.x;
    o.y = (v.y - mu) * rs * gg.y + bb.y;
    o.z = (v.z - mu) * rs * gg.z + bb.z;
    o.w = (v.w - mu) * rs * gg.w + bb.w;
    *(float4*)&of[(size_t)i * 4] = o;
    if (ob) {
      U16x4 u{f2bf(o.x), f2bf(o.y), f2bf(o.z), f2bf(o.w)};
      *(U16x4*)&ob[(size_t)i * 4] = u;
    }
  }
}

// ---------------------------------------------------------------------------
extern "C" void kernel_launch(void* const* d_in, const int* in_sizes, int n_in,
                              void* d_out, int out_size, void* d_ws, size_t ws_size,
                              hipStream_t stream) {
  const float* src = (const float*)d_in[0];
  const float* Wq = (const float*)d_in[1];
  const float* bq = (const float*)d_in[2];
  const float* Wk = (const float*)d_in[3];
  const float* bk = (const float*)d_in[4];
  const float* Wv = (const float*)d_in[5];
  const float* bv = (const float*)d_in[6];
  const float* Wo = (const float*)d_in[7];
  const float* bo = (const float*)d_in[8];
  const float* W1 = (const float*)d_in[9];
  const float* b1 = (const float*)d_in[10];
  const float* W2 = (const float*)d_in[11];
  const float* b2 = (const float*)d_in[12];
  const float* g1 = (const float*)d_in[13];
  const float* be1 = (const float*)d_in[14];
  const float* g2 = (const float*)d_in[15];
  const float* be2 = (const float*)d_in[16];
  float* dout = (float*)d_out;
  char* ws = (char*)d_ws;

  const size_t MB = 1024 * 1024;
  uint16_t* wq_t = (uint16_t*)(ws + 0 * MB);
  uint16_t* wk_t = (uint16_t*)(ws + 2 * MB);
  uint16_t* wv_t = (uint16_t*)(ws + 4 * MB);
  uint16_t* wo_t = (uint16_t*)(ws + 6 * MB);
  uint16_t* w1_t = (uint16_t*)(ws + 8 * MB);   // [4096][1024]
  uint16_t* w2_t = (uint16_t*)(ws + 16 * MB);  // [1024][4096]
  uint16_t* m1bf = (uint16_t*)(ws + 24 * MB);  // final m1 bf16 (phase-B KV src)
  uint16_t* mod2 = (uint16_t*)(ws + 56 * MB);
  uint16_t* QB = (uint16_t*)(ws + 88 * MB);
  uint16_t* KB = (uint16_t*)(ws + 120 * MB);
  uint16_t* VB = (uint16_t*)(ws + 152 * MB);
  uint16_t* ATT = (uint16_t*)(ws + 184 * MB);
  uint16_t* Hbf = QB;  // 128 MB FFN hidden aliases QB..ATT (dead by then)
  uint16_t* mod1 = (uint16_t*)(ws + 216 * MB);
  float* XA = (float*)(ws + 248 * MB);
  float* YF = (float*)(ws + 312 * MB);
  uint16_t* YBF = (uint16_t*)(ws + 376 * MB);
  // total: 408 MB

  dim3 tb(32, 32);
  transpose_cvt<<<dim3(32, 32), tb, 0, stream>>>(Wq, wq_t, 1024, 1024);
  transpose_cvt<<<dim3(32, 32), tb, 0, stream>>>(Wk, wk_t, 1024, 1024);
  transpose_cvt<<<dim3(32, 32), tb, 0, stream>>>(Wv, wv_t, 1024, 1024);
  transpose_cvt<<<dim3(32, 32), tb, 0, stream>>>(Wo, wo_t, 1024, 1024);
  transpose_cvt<<<dim3(128, 32), tb, 0, stream>>>(W1, w1_t, 1024, 4096);
  transpose_cvt<<<dim3(32, 128), tb, 0, stream>>>(W2, w2_t, 4096, 1024);
  cvt_modal<<<16384, 256, 0, stream>>>(src, mod1, mod2);

  auto phase = [&](const uint16_t* qsrc, const uint16_t* kvsrc, int soff,
                   float* out_f, uint16_t* out_bf) {
    // projections: M=16384, N=1024, K=1024 -> 256 blocks, nbn=4
    gemm256<0, false, false><<<256, 1024, 0, stream>>>(qsrc, wq_t, bq, nullptr, QB,
                                                       1024, 1024, 4, 0);
    gemm256<0, false, false><<<256, 1024, 0, stream>>>(kvsrc, wk_t, bk, nullptr, KB,
                                                       1024, 1024, 4, 0);
    gemm256<0, false, false><<<256, 1024, 0, stream>>>(kvsrc, wv_t, bv, nullptr, VB,
                                                       1024, 1024, 4, 0);
    attn_kern<<<2048, 256, 0, stream>>>(QB, KB, VB, ATT);
    // out-proj + residual from src slice
    gemm256<2, false, true><<<256, 1024, 0, stream>>>(ATT, wo_t, bo, src, XA,
                                                      1024, 1024, 4, soff);
    ln2d<<<128, 512, 0, stream>>>(XA, g1, be1, YF, 131072, YBF);
    // FFN: 16384x4096x1024 (nbn=16) then 16384x1024x4096 (nbn=4)
    gemm256<0, true, false><<<1024, 1024, 0, stream>>>(YBF, w1_t, b1, nullptr, Hbf,
                                                       4096, 1024, 16, 0);
    gemm256<1, false, true><<<256, 1024, 0, stream>>>(Hbf, w2_t, b2, YF, XA,
                                                      1024, 4096, 4, 0);
    ln2d<<<128, 512, 0, stream>>>(XA, g2, be2, out_f, 262144, out_bf);
  };

  phase(mod1, mod2, 0, dout, m1bf);
  phase(mod2, m1bf, 128, dout + 131072, nullptr);

  (void)in_sizes; (void)n_in; (void)out_size; (void)ws_size;
}